// Round 1
// baseline (4526.982 us; speedup 1.0000x reference)
//
#include <hip/hip_runtime.h>
#include <math.h>

// ---------------------------------------------------------------------------
// HOGGraphNet: 2x GCNConv(+LN+ReLU) -> GATConv(4 heads, mean) -> mean/max pool
// N=50000 nodes, E=600000 edges, D=128, H=4, G=64 graphs. fp32 throughout.
// ---------------------------------------------------------------------------

#define TPB 256

__device__ __forceinline__ float lrelu(float x) { return x > 0.f ? x : 0.2f * x; }

// atomic float max handling mixed signs:
// nonneg floats ordered as int; neg floats reverse-ordered as uint.
__device__ __forceinline__ void atomicMaxF(float* a, float v) {
    if (v >= 0.f) atomicMax((int*)a, __float_as_int(v));
    else          atomicMin((unsigned int*)a, __float_as_uint(v));
}

// ---------------- degree ----------------
__global__ __launch_bounds__(TPB) void k_fill1(float* p, int n) {
    int i = blockIdx.x * TPB + threadIdx.x;
    if (i < n) p[i] = 1.f;
}
__global__ __launch_bounds__(TPB) void k_deg_edges(const int* __restrict__ dst,
                                                   float* __restrict__ deg, int e) {
    int i = blockIdx.x * TPB + threadIdx.x;
    if (i < e) atomicAdd(&deg[dst[i]], 1.f);
}
__global__ __launch_bounds__(TPB) void k_rsqrt_ip(float* p, int n) {
    int i = blockIdx.x * TPB + threadIdx.x;
    if (i < n) p[i] = rsqrtf(p[i]);
}

// ---------------- GEMM: C[r,c] = sum_k A[r,k] * W[k,c], K = 128 -------------
// block=256: 32 col-quads (128-col tile) x 8 rows, 4 row-iterations -> 32 rows/blk
__global__ __launch_bounds__(TPB) void k_gemm(const float* __restrict__ A,
                                              const float* __restrict__ W,
                                              float* __restrict__ C,
                                              int nrows, int ocols) {
    int cq = threadIdx.x & 31;      // col-quad within 128-col tile
    int ro = threadIdx.x >> 5;      // 0..7
    int ctile = blockIdx.y << 7;    // col tile base
    int wq = ocols >> 2;            // float4s per W row
    int cquad = (ctile >> 2) + cq;
    const float4* A4 = (const float4*)A;
    const float4* W4 = (const float4*)W;
    int row_base = blockIdx.x << 5;
    for (int rr = 0; rr < 4; ++rr) {
        int row = row_base + rr * 8 + ro;
        if (row >= nrows) continue;
        float4 acc = make_float4(0.f, 0.f, 0.f, 0.f);
        const float4* arow = A4 + row * 32;
#pragma unroll 8
        for (int k4 = 0; k4 < 32; ++k4) {
            float4 av = arow[k4];
            float4 w0 = W4[(k4 * 4 + 0) * wq + cquad];
            float4 w1 = W4[(k4 * 4 + 1) * wq + cquad];
            float4 w2 = W4[(k4 * 4 + 2) * wq + cquad];
            float4 w3 = W4[(k4 * 4 + 3) * wq + cquad];
            acc.x += av.x * w0.x + av.y * w1.x + av.z * w2.x + av.w * w3.x;
            acc.y += av.x * w0.y + av.y * w1.y + av.z * w2.y + av.w * w3.y;
            acc.z += av.x * w0.z + av.y * w1.z + av.z * w2.z + av.w * w3.z;
            acc.w += av.x * w0.w + av.y * w1.w + av.z * w2.w + av.w * w3.w;
        }
        ((float4*)C)[row * wq + cquad] = acc;
    }
}

// ---------------- GCN edge scatter: agg[dst] += dis[s]*dis[d] * h[src] ------
// 32 lanes per edge, float4 gather + 4 atomicAdds
__global__ __launch_bounds__(TPB) void k_gcn_agg(const float* __restrict__ h,
                                                 const int* __restrict__ src,
                                                 const int* __restrict__ dst,
                                                 const float* __restrict__ dis,
                                                 float* __restrict__ agg, int ne) {
    int t = blockIdx.x * TPB + threadIdx.x;
    int e = t >> 5, lane = t & 31;
    if (e >= ne) return;
    int s = src[e], d = dst[e];
    float norm = dis[s] * dis[d];
    float4 hv = ((const float4*)h)[s * 32 + lane];
    float* out = agg + d * 128 + lane * 4;
    atomicAdd(out + 0, norm * hv.x);
    atomicAdd(out + 1, norm * hv.y);
    atomicAdd(out + 2, norm * hv.z);
    atomicAdd(out + 3, norm * hv.w);
}

// ---------------- fused self-loop + bias + LayerNorm + ReLU -----------------
// one wave (64 lanes) per row, 2 elems/lane, shuffle reduction
__global__ __launch_bounds__(TPB) void k_ln_relu(const float* __restrict__ agg,
                                                 const float* __restrict__ h,
                                                 const float* __restrict__ dis,
                                                 const float* __restrict__ b,
                                                 const float* __restrict__ g,
                                                 const float* __restrict__ beta,
                                                 float* __restrict__ out, int n) {
    int wave = (blockIdx.x * TPB + threadIdx.x) >> 6;
    int lane = threadIdx.x & 63;
    if (wave >= n) return;
    int row = wave;
    float ds = dis[row];
    float sl = ds * ds;  // self-loop norm = 1/deg
    float2 a  = ((const float2*)(agg + row * 128))[lane];
    float2 hv = ((const float2*)(h + row * 128))[lane];
    float2 bv = ((const float2*)b)[lane];
    float vx = a.x + sl * hv.x + bv.x;
    float vy = a.y + sl * hv.y + bv.y;
    float s = vx + vy, sq = vx * vx + vy * vy;
#pragma unroll
    for (int o = 32; o > 0; o >>= 1) {
        s  += __shfl_xor(s, o);
        sq += __shfl_xor(sq, o);
    }
    float mu = s * (1.f / 128.f);
    float var = sq * (1.f / 128.f) - mu * mu;
    float rstd = rsqrtf(var + 1e-5f);
    float2 gv  = ((const float2*)g)[lane];
    float2 btv = ((const float2*)beta)[lane];
    float ox = fmaxf((vx - mu) * rstd * gv.x + btv.x, 0.f);
    float oy = fmaxf((vy - mu) * rstd * gv.y + btv.y, 0.f);
    ((float2*)(out + row * 128))[lane] = make_float2(ox, oy);
}

// ---------------- GAT attention dots: a_s[n,h], a_d[n,h] --------------------
// one wave per node; 16 lanes per head, 8 elems/lane
__global__ __launch_bounds__(TPB) void k_att_dots(const float* __restrict__ hg,
                                                  const float* __restrict__ att_s,
                                                  const float* __restrict__ att_d,
                                                  float* __restrict__ a_s,
                                                  float* __restrict__ a_d, int n) {
    int wave = (blockIdx.x * TPB + threadIdx.x) >> 6;
    int lane = threadIdx.x & 63;
    if (wave >= n) return;
    int h = lane >> 4, j = lane & 15;
    const float4* hv4 = (const float4*)(hg + wave * 512 + h * 128 + j * 8);
    const float4* s4  = (const float4*)(att_s + h * 128 + j * 8);
    const float4* d4  = (const float4*)(att_d + h * 128 + j * 8);
    float4 h0 = hv4[0], h1 = hv4[1];
    float4 s0 = s4[0], s1 = s4[1];
    float4 d0 = d4[0], d1 = d4[1];
    float ps = h0.x * s0.x + h0.y * s0.y + h0.z * s0.z + h0.w * s0.w
             + h1.x * s1.x + h1.y * s1.y + h1.z * s1.z + h1.w * s1.w;
    float pd = h0.x * d0.x + h0.y * d0.y + h0.z * d0.z + h0.w * d0.w
             + h1.x * d1.x + h1.y * d1.y + h1.z * d1.z + h1.w * d1.w;
#pragma unroll
    for (int o = 8; o > 0; o >>= 1) {
        ps += __shfl_xor(ps, o);
        pd += __shfl_xor(pd, o);
    }
    if (j == 0) {
        a_s[wave * 4 + h] = ps;
        a_d[wave * 4 + h] = pd;
    }
}

// m init with self-loop edge value (every node has one)
__global__ __launch_bounds__(TPB) void k_m_init(const float* __restrict__ a_s,
                                                const float* __restrict__ a_d,
                                                float* __restrict__ m, int n4) {
    int i = blockIdx.x * TPB + threadIdx.x;
    if (i < n4) m[i] = lrelu(a_s[i] + a_d[i]);
}
__global__ __launch_bounds__(TPB) void k_m_edges(const int* __restrict__ src,
                                                 const int* __restrict__ dst,
                                                 const float* __restrict__ a_s,
                                                 const float* __restrict__ a_d,
                                                 float* __restrict__ m, int ne) {
    int t = blockIdx.x * TPB + threadIdx.x;
    if (t >= ne * 4) return;
    int e = t >> 2, h = t & 3;
    int s = src[e], d = dst[e];
    float v = lrelu(a_s[s * 4 + h] + a_d[d * 4 + h]);
    atomicMaxF(&m[d * 4 + h], v);
}
__global__ __launch_bounds__(TPB) void k_den_init(const float* __restrict__ a_s,
                                                  const float* __restrict__ a_d,
                                                  const float* __restrict__ m,
                                                  float* __restrict__ den, int n4) {
    int i = blockIdx.x * TPB + threadIdx.x;
    if (i < n4) den[i] = expf(lrelu(a_s[i] + a_d[i]) - m[i]);
}
__global__ __launch_bounds__(TPB) void k_den_edges(const int* __restrict__ src,
                                                   const int* __restrict__ dst,
                                                   const float* __restrict__ a_s,
                                                   const float* __restrict__ a_d,
                                                   const float* __restrict__ m,
                                                   float* __restrict__ den, int ne) {
    int t = blockIdx.x * TPB + threadIdx.x;
    if (t >= ne * 4) return;
    int e = t >> 2, h = t & 3;
    int s = src[e], d = dst[e];
    float v = lrelu(a_s[s * 4 + h] + a_d[d * 4 + h]);
    atomicAdd(&den[d * 4 + h], expf(v - m[d * 4 + h]));
}
// wself = 0.25*exp(e_self - m)/den ; den <- 0.25/den (inverse for edge pass)
__global__ __launch_bounds__(TPB) void k_wfin(const float* __restrict__ a_s,
                                              const float* __restrict__ a_d,
                                              const float* __restrict__ m,
                                              float* __restrict__ den,
                                              float* __restrict__ wself, int n4) {
    int i = blockIdx.x * TPB + threadIdx.x;
    if (i < n4) {
        float dv = den[i];
        wself[i] = 0.25f * expf(lrelu(a_s[i] + a_d[i]) - m[i]) / dv;
        den[i] = 0.25f / dv;
    }
}
// acc init with self-loop contribution (no atomics needed; one writer/elem)
__global__ __launch_bounds__(TPB) void k_att_acc_init(const float* __restrict__ hg,
                                                      const float* __restrict__ wself,
                                                      float* __restrict__ acc, int n) {
    int t = blockIdx.x * TPB + threadIdx.x;
    int nn = t >> 5, lane = t & 31;
    if (nn >= n) return;
    const float4* hgs = (const float4*)(hg + nn * 512);
    float w0 = wself[nn * 4 + 0], w1 = wself[nn * 4 + 1];
    float w2 = wself[nn * 4 + 2], w3 = wself[nn * 4 + 3];
    float4 h0 = hgs[0 * 32 + lane], h1 = hgs[1 * 32 + lane];
    float4 h2 = hgs[2 * 32 + lane], h3 = hgs[3 * 32 + lane];
    float4 o;
    o.x = w0 * h0.x + w1 * h1.x + w2 * h2.x + w3 * h3.x;
    o.y = w0 * h0.y + w1 * h1.y + w2 * h2.y + w3 * h3.y;
    o.z = w0 * h0.z + w1 * h1.z + w2 * h2.z + w3 * h3.z;
    o.w = w0 * h0.w + w1 * h1.w + w2 * h2.w + w3 * h3.w;
    ((float4*)acc)[nn * 32 + lane] = o;
}
__global__ __launch_bounds__(TPB) void k_att_acc_edges(const float* __restrict__ hg,
                                                       const int* __restrict__ src,
                                                       const int* __restrict__ dst,
                                                       const float* __restrict__ a_s,
                                                       const float* __restrict__ a_d,
                                                       const float* __restrict__ m,
                                                       const float* __restrict__ deninv,
                                                       float* __restrict__ acc, int ne) {
    int t = blockIdx.x * TPB + threadIdx.x;
    int e = t >> 5, lane = t & 31;
    if (e >= ne) return;
    int s = src[e], d = dst[e];
    float w[4];
#pragma unroll
    for (int h = 0; h < 4; ++h) {
        float v = lrelu(a_s[s * 4 + h] + a_d[d * 4 + h]);
        w[h] = expf(v - m[d * 4 + h]) * deninv[d * 4 + h];
    }
    const float4* hgs = (const float4*)(hg + s * 512);
    float4 o = make_float4(0.f, 0.f, 0.f, 0.f);
#pragma unroll
    for (int h = 0; h < 4; ++h) {
        float4 hv = hgs[h * 32 + lane];
        o.x += w[h] * hv.x; o.y += w[h] * hv.y;
        o.z += w[h] * hv.z; o.w += w[h] * hv.w;
    }
    float* out = acc + d * 128 + lane * 4;
    atomicAdd(out + 0, o.x);
    atomicAdd(out + 1, o.y);
    atomicAdd(out + 2, o.z);
    atomicAdd(out + 3, o.w);
}

// ---------------- final bias+relu, write node embeddings, pool atomics ------
__global__ __launch_bounds__(TPB) void k_final_pool(const float* __restrict__ acc,
                                                    const float* __restrict__ gat_b,
                                                    const int* __restrict__ batch,
                                                    float* __restrict__ node_out,
                                                    float* __restrict__ mean_acc,
                                                    float* __restrict__ max_acc,
                                                    float* __restrict__ cnt, int n) {
    int t = blockIdx.x * TPB + threadIdx.x;
    int nn = t >> 5, lane = t & 31;
    if (nn >= n) return;
    int g = batch[nn];
    float4 a = ((const float4*)acc)[nn * 32 + lane];
    float4 b = ((const float4*)gat_b)[lane];
    float4 o;
    o.x = fmaxf(a.x + b.x, 0.f);
    o.y = fmaxf(a.y + b.y, 0.f);
    o.z = fmaxf(a.z + b.z, 0.f);
    o.w = fmaxf(a.w + b.w, 0.f);
    ((float4*)node_out)[nn * 32 + lane] = o;
    float* ma = mean_acc + g * 128 + lane * 4;
    atomicAdd(ma + 0, o.x); atomicAdd(ma + 1, o.y);
    atomicAdd(ma + 2, o.z); atomicAdd(ma + 3, o.w);
    float* mx = max_acc + g * 128 + lane * 4;
    // post-relu values >= 0, max buffer zero-initialized -> int compare valid
    atomicMax((int*)(mx + 0), __float_as_int(o.x));
    atomicMax((int*)(mx + 1), __float_as_int(o.y));
    atomicMax((int*)(mx + 2), __float_as_int(o.z));
    atomicMax((int*)(mx + 3), __float_as_int(o.w));
    if (lane == 0) atomicAdd(&cnt[g], 1.f);
}
__global__ __launch_bounds__(TPB) void k_pool_final(const float* __restrict__ mean_acc,
                                                    const float* __restrict__ max_acc,
                                                    const float* __restrict__ cnt,
                                                    float* __restrict__ gout, int g128) {
    int i = blockIdx.x * TPB + threadIdx.x;
    if (i >= g128) return;
    int g = i >> 7, d = i & 127;
    float c = fmaxf(cnt[g], 1.f);
    gout[g * 256 + d] = mean_acc[i] / c;
    gout[g * 256 + 128 + d] = max_acc[i];
}

// ---------------------------------------------------------------------------
extern "C" void kernel_launch(void* const* d_in, const int* in_sizes, int n_in,
                              void* d_out, int out_size, void* d_ws, size_t ws_size,
                              hipStream_t stream) {
    const float* x       = (const float*)d_in[0];
    const int*   ei      = (const int*)d_in[1];
    const int*   batch   = (const int*)d_in[2];
    const float* W1      = (const float*)d_in[3];
    const float* b1      = (const float*)d_in[4];
    const float* g1      = (const float*)d_in[5];
    const float* beta1   = (const float*)d_in[6];
    const float* W2      = (const float*)d_in[7];
    const float* b2      = (const float*)d_in[8];
    const float* g2      = (const float*)d_in[9];
    const float* beta2   = (const float*)d_in[10];
    const float* gat_W   = (const float*)d_in[11];
    const float* att_src = (const float*)d_in[12];
    const float* att_dst = (const float*)d_in[13];
    const float* gat_b   = (const float*)d_in[14];

    const int N = in_sizes[0] / 128;
    const int E = in_sizes[1] / 2;
    const int G = (out_size - N * 128) / 256;
    const int* src = ei;
    const int* dst = ei + E;

    float* ws = (float*)d_ws;
    float* dis      = ws; ws += N;          // N*4 bytes, stays 16B-aligned (N=50000)
    float* A        = ws; ws += N * 128;    // gemm out / gat accumulator
    float* B        = ws; ws += N * 128;    // agg1 / h1
    float* C        = ws; ws += N * 128;    // agg2 / h2 (GCN output)
    float* hg       = ws; ws += N * 512;    // GAT transformed features
    float* a_s      = ws; ws += N * 4;
    float* a_d      = ws; ws += N * 4;
    float* m        = ws; ws += N * 4;
    float* den      = ws; ws += N * 4;
    float* wself    = ws; ws += N * 4;
    float* mean_acc = ws; ws += G * 128;
    float* max_acc  = ws; ws += G * 128;
    float* cnt      = ws; ws += G;

    float* gout = (float*)d_out;            // [G, 256]
    float* node_out = gout + G * 256;       // [N, 128]

    auto cdiv = [](long a, long b) { return (int)((a + b - 1) / b); };

    // degrees (self-loop => init 1)
    k_fill1<<<cdiv(N, TPB), TPB, 0, stream>>>(dis, N);
    k_deg_edges<<<cdiv(E, TPB), TPB, 0, stream>>>(dst, dis, E);
    k_rsqrt_ip<<<cdiv(N, TPB), TPB, 0, stream>>>(dis, N);

    // GCN layer 1
    k_gemm<<<dim3(cdiv(N, 32), 1), TPB, 0, stream>>>(x, W1, A, N, 128);
    hipMemsetAsync(B, 0, (size_t)N * 128 * 4, stream);
    k_gcn_agg<<<cdiv((long)E * 32, TPB), TPB, 0, stream>>>(A, src, dst, dis, B, E);
    k_ln_relu<<<cdiv((long)N * 64, TPB), TPB, 0, stream>>>(B, A, dis, b1, g1, beta1, B, N);

    // GCN layer 2
    k_gemm<<<dim3(cdiv(N, 32), 1), TPB, 0, stream>>>(B, W2, A, N, 128);
    hipMemsetAsync(C, 0, (size_t)N * 128 * 4, stream);
    k_gcn_agg<<<cdiv((long)E * 32, TPB), TPB, 0, stream>>>(A, src, dst, dis, C, E);
    k_ln_relu<<<cdiv((long)N * 64, TPB), TPB, 0, stream>>>(C, A, dis, b2, g2, beta2, C, N);

    // GAT
    k_gemm<<<dim3(cdiv(N, 32), 4), TPB, 0, stream>>>(C, gat_W, hg, N, 512);
    k_att_dots<<<cdiv((long)N * 64, TPB), TPB, 0, stream>>>(hg, att_src, att_dst, a_s, a_d, N);
    k_m_init<<<cdiv((long)N * 4, TPB), TPB, 0, stream>>>(a_s, a_d, m, N * 4);
    k_m_edges<<<cdiv((long)E * 4, TPB), TPB, 0, stream>>>(src, dst, a_s, a_d, m, E);
    k_den_init<<<cdiv((long)N * 4, TPB), TPB, 0, stream>>>(a_s, a_d, m, den, N * 4);
    k_den_edges<<<cdiv((long)E * 4, TPB), TPB, 0, stream>>>(src, dst, a_s, a_d, m, den, E);
    k_wfin<<<cdiv((long)N * 4, TPB), TPB, 0, stream>>>(a_s, a_d, m, den, wself, N * 4);
    k_att_acc_init<<<cdiv((long)N * 32, TPB), TPB, 0, stream>>>(hg, wself, A, N);
    k_att_acc_edges<<<cdiv((long)E * 32, TPB), TPB, 0, stream>>>(hg, src, dst, a_s, a_d, m, den, A, E);

    // final + pooling
    hipMemsetAsync(mean_acc, 0, (size_t)(G * 256 + G) * 4, stream);
    k_final_pool<<<cdiv((long)N * 32, TPB), TPB, 0, stream>>>(A, gat_b, batch, node_out,
                                                              mean_acc, max_acc, cnt, N);
    k_pool_final<<<cdiv((long)G * 128, TPB), TPB, 0, stream>>>(mean_acc, max_acc, cnt, gout, G * 128);
}

// Round 2
// 1415.035 us; speedup vs baseline: 3.1992x; 3.1992x over previous
//
#include <hip/hip_runtime.h>
#include <math.h>

// ---------------------------------------------------------------------------
// HOGGraphNet: 2x GCNConv(+LN+ReLU) -> GATConv(4 heads, mean) -> mean/max pool
// N=50000, E=600000, D=128, H=4, G=64. fp32. CSR gather-side aggregation.
// ---------------------------------------------------------------------------

#define TPB 256

__device__ __forceinline__ float lrelu(float x) { return x > 0.f ? x : 0.2f * x; }

// ---------------- CSR build ----------------
__global__ __launch_bounds__(TPB) void k_hist(const int* __restrict__ dst,
                                              int* __restrict__ deg, int e) {
    int i = blockIdx.x * TPB + threadIdx.x;
    if (i < e) atomicAdd(&deg[dst[i]], 1);
}

// single block, 1024 threads: exclusive scan of deg -> row_start/cursor, dis
__global__ __launch_bounds__(1024) void k_scan(const int* __restrict__ deg,
                                               int* __restrict__ row_start,
                                               int* __restrict__ cursor,
                                               float* __restrict__ dis,
                                               int n, int e_total) {
    __shared__ int sm[1024];
    int t = threadIdx.x;
    int chunk = (n + 1023) >> 10;
    int lo = t * chunk, hi = min(lo + chunk, n);
    int s = 0;
    for (int i = lo; i < hi; ++i) s += deg[i];
    sm[t] = s;
    __syncthreads();
    for (int off = 1; off < 1024; off <<= 1) {
        int v = 0;
        if (t >= off) v = sm[t - off];
        __syncthreads();
        if (t >= off) sm[t] += v;
        __syncthreads();
    }
    int run = (t == 0) ? 0 : sm[t - 1];
    for (int i = lo; i < hi; ++i) {
        int d = deg[i];
        row_start[i] = run;
        cursor[i] = run;
        dis[i] = rsqrtf((float)(d + 1));  // +1 self loop
        run += d;
    }
    if (t == 0) row_start[n] = e_total;
}

__global__ __launch_bounds__(TPB) void k_scatter(const int* __restrict__ src,
                                                 const int* __restrict__ dst,
                                                 int* __restrict__ cursor,
                                                 int* __restrict__ csr_src, int e) {
    int i = blockIdx.x * TPB + threadIdx.x;
    if (i < e) {
        int p = atomicAdd(&cursor[dst[i]], 1);
        csr_src[p] = src[i];
    }
}

// ---------------- GEMM: C[r,c] = sum_k A[r,k] * W[k,c], K = 128 -------------
__global__ __launch_bounds__(TPB) void k_gemm(const float* __restrict__ A,
                                              const float* __restrict__ W,
                                              float* __restrict__ C,
                                              int nrows, int ocols) {
    int cq = threadIdx.x & 31;
    int ro = threadIdx.x >> 5;
    int ctile = blockIdx.y << 7;
    int wq = ocols >> 2;
    int cquad = (ctile >> 2) + cq;
    const float4* A4 = (const float4*)A;
    const float4* W4 = (const float4*)W;
    int row_base = blockIdx.x << 5;
    for (int rr = 0; rr < 4; ++rr) {
        int row = row_base + rr * 8 + ro;
        if (row >= nrows) continue;
        float4 acc = make_float4(0.f, 0.f, 0.f, 0.f);
        const float4* arow = A4 + row * 32;
#pragma unroll 8
        for (int k4 = 0; k4 < 32; ++k4) {
            float4 av = arow[k4];
            float4 w0 = W4[(k4 * 4 + 0) * wq + cquad];
            float4 w1 = W4[(k4 * 4 + 1) * wq + cquad];
            float4 w2 = W4[(k4 * 4 + 2) * wq + cquad];
            float4 w3 = W4[(k4 * 4 + 3) * wq + cquad];
            acc.x += av.x * w0.x + av.y * w1.x + av.z * w2.x + av.w * w3.x;
            acc.y += av.x * w0.y + av.y * w1.y + av.z * w2.y + av.w * w3.y;
            acc.z += av.x * w0.z + av.y * w1.z + av.z * w2.z + av.w * w3.z;
            acc.w += av.x * w0.w + av.y * w1.w + av.z * w2.w + av.w * w3.w;
        }
        ((float4*)C)[row * wq + cquad] = acc;
    }
}

// ---------------- fused GCN: gather + self + bias + LN + ReLU ---------------
// one wave per node, 2 elems/lane
__global__ __launch_bounds__(TPB) void k_gcn_fused(const float* __restrict__ h,
                                                   const int* __restrict__ csr_src,
                                                   const int* __restrict__ row_start,
                                                   const float* __restrict__ dis,
                                                   const float* __restrict__ b,
                                                   const float* __restrict__ g,
                                                   const float* __restrict__ beta,
                                                   float* __restrict__ out, int n) {
    int node = (blockIdx.x * TPB + threadIdx.x) >> 6;
    int lane = threadIdx.x & 63;
    if (node >= n) return;
    int s0 = row_start[node], s1 = row_start[node + 1];
    float dn = dis[node];
    const float2* h2 = (const float2*)h;
    float2 acc = make_float2(0.f, 0.f);
    for (int i = s0; i < s1; ++i) {
        int s = csr_src[i];
        float w = dis[s];
        float2 hv = h2[s * 64 + lane];
        acc.x += w * hv.x;
        acc.y += w * hv.y;
    }
    // norm = dis[s]*dis[node]: dn factored out of the sum
    float sl = dn * dn;  // self-loop norm
    float2 hv = h2[node * 64 + lane];
    float2 bv = ((const float2*)b)[lane];
    float vx = dn * acc.x + sl * hv.x + bv.x;
    float vy = dn * acc.y + sl * hv.y + bv.y;
    float s = vx + vy, sq = vx * vx + vy * vy;
#pragma unroll
    for (int o = 32; o > 0; o >>= 1) {
        s  += __shfl_xor(s, o);
        sq += __shfl_xor(sq, o);
    }
    float mu = s * (1.f / 128.f);
    float var = sq * (1.f / 128.f) - mu * mu;
    float rstd = rsqrtf(var + 1e-5f);
    float2 gv  = ((const float2*)g)[lane];
    float2 btv = ((const float2*)beta)[lane];
    float ox = fmaxf((vx - mu) * rstd * gv.x + btv.x, 0.f);
    float oy = fmaxf((vy - mu) * rstd * gv.y + btv.y, 0.f);
    ((float2*)(out + node * 128))[lane] = make_float2(ox, oy);
}

// ---------------- GAT attention dots ----------------------------------------
__global__ __launch_bounds__(TPB) void k_att_dots(const float* __restrict__ hg,
                                                  const float* __restrict__ att_s,
                                                  const float* __restrict__ att_d,
                                                  float* __restrict__ a_s,
                                                  float* __restrict__ a_d, int n) {
    int wave = (blockIdx.x * TPB + threadIdx.x) >> 6;
    int lane = threadIdx.x & 63;
    if (wave >= n) return;
    int h = lane >> 4, j = lane & 15;
    const float4* hv4 = (const float4*)(hg + (size_t)wave * 512 + h * 128 + j * 8);
    const float4* s4  = (const float4*)(att_s + h * 128 + j * 8);
    const float4* d4  = (const float4*)(att_d + h * 128 + j * 8);
    float4 h0 = hv4[0], h1 = hv4[1];
    float4 s0 = s4[0], s1 = s4[1];
    float4 d0 = d4[0], d1 = d4[1];
    float ps = h0.x * s0.x + h0.y * s0.y + h0.z * s0.z + h0.w * s0.w
             + h1.x * s1.x + h1.y * s1.y + h1.z * s1.z + h1.w * s1.w;
    float pd = h0.x * d0.x + h0.y * d0.y + h0.z * d0.z + h0.w * d0.w
             + h1.x * d1.x + h1.y * d1.y + h1.z * d1.z + h1.w * d1.w;
#pragma unroll
    for (int o = 8; o > 0; o >>= 1) {
        ps += __shfl_xor(ps, o);
        pd += __shfl_xor(pd, o);
    }
    if (j == 0) {
        a_s[wave * 4 + h] = ps;
        a_d[wave * 4 + h] = pd;
    }
}

// ---------------- fused GAT: segment softmax + weighted gather + head mean --
// one wave per node; phases: max, denom, feature accumulation
__global__ __launch_bounds__(TPB) void k_gat_fused(const float* __restrict__ hg,
                                                   const float* __restrict__ a_s,
                                                   const float* __restrict__ a_d,
                                                   const int* __restrict__ csr_src,
                                                   const int* __restrict__ row_start,
                                                   float* __restrict__ out, int n) {
    int node = (blockIdx.x * TPB + threadIdx.x) >> 6;
    int lane = threadIdx.x & 63;
    if (node >= n) return;
    int s0 = row_start[node], s1 = row_start[node + 1];
    const float4* as4 = (const float4*)a_s;
    float4 ad = ((const float4*)a_d)[node];
    float4 asn = as4[node];
    float4 selfv;
    selfv.x = lrelu(asn.x + ad.x);
    selfv.y = lrelu(asn.y + ad.y);
    selfv.z = lrelu(asn.z + ad.z);
    selfv.w = lrelu(asn.w + ad.w);
    // phase 1: max over edges (+ self), lanes strided over edges
    float4 mx = selfv;
    for (int i = s0 + lane; i < s1; i += 64) {
        int s = csr_src[i];
        float4 a = as4[s];
        mx.x = fmaxf(mx.x, lrelu(a.x + ad.x));
        mx.y = fmaxf(mx.y, lrelu(a.y + ad.y));
        mx.z = fmaxf(mx.z, lrelu(a.z + ad.z));
        mx.w = fmaxf(mx.w, lrelu(a.w + ad.w));
    }
#pragma unroll
    for (int o = 32; o > 0; o >>= 1) {
        mx.x = fmaxf(mx.x, __shfl_xor(mx.x, o));
        mx.y = fmaxf(mx.y, __shfl_xor(mx.y, o));
        mx.z = fmaxf(mx.z, __shfl_xor(mx.z, o));
        mx.w = fmaxf(mx.w, __shfl_xor(mx.w, o));
    }
    // phase 2: denom
    float4 den = make_float4(0.f, 0.f, 0.f, 0.f);
    for (int i = s0 + lane; i < s1; i += 64) {
        int s = csr_src[i];
        float4 a = as4[s];
        den.x += __expf(lrelu(a.x + ad.x) - mx.x);
        den.y += __expf(lrelu(a.y + ad.y) - mx.y);
        den.z += __expf(lrelu(a.z + ad.z) - mx.z);
        den.w += __expf(lrelu(a.w + ad.w) - mx.w);
    }
#pragma unroll
    for (int o = 32; o > 0; o >>= 1) {
        den.x += __shfl_xor(den.x, o);
        den.y += __shfl_xor(den.y, o);
        den.z += __shfl_xor(den.z, o);
        den.w += __shfl_xor(den.w, o);
    }
    float4 ws;  // self weights (exp(self - mx))
    ws.x = __expf(selfv.x - mx.x);
    ws.y = __expf(selfv.y - mx.y);
    ws.z = __expf(selfv.z - mx.z);
    ws.w = __expf(selfv.w - mx.w);
    den.x += ws.x; den.y += ws.y; den.z += ws.z; den.w += ws.w;
    float4 winv;  // 0.25/den folds the head mean
    winv.x = 0.25f / den.x;
    winv.y = 0.25f / den.y;
    winv.z = 0.25f / den.z;
    winv.w = 0.25f / den.w;
    // phase 3: weighted feature accumulation, feature-parallel (2 floats/lane)
    const float2* hg2 = (const float2*)hg;
    float2 acc;
    {
        float4 w = make_float4(ws.x * winv.x, ws.y * winv.y, ws.z * winv.z, ws.w * winv.w);
        const float2* row = hg2 + (size_t)node * 256;
        float2 e0 = row[lane], e1 = row[64 + lane], e2 = row[128 + lane], e3 = row[192 + lane];
        acc.x = w.x * e0.x + w.y * e1.x + w.z * e2.x + w.w * e3.x;
        acc.y = w.x * e0.y + w.y * e1.y + w.z * e2.y + w.w * e3.y;
    }
    for (int i = s0; i < s1; ++i) {
        int s = csr_src[i];
        float4 a = as4[s];
        float4 w;
        w.x = __expf(lrelu(a.x + ad.x) - mx.x) * winv.x;
        w.y = __expf(lrelu(a.y + ad.y) - mx.y) * winv.y;
        w.z = __expf(lrelu(a.z + ad.z) - mx.z) * winv.z;
        w.w = __expf(lrelu(a.w + ad.w) - mx.w) * winv.w;
        const float2* row = hg2 + (size_t)s * 256;
        float2 e0 = row[lane], e1 = row[64 + lane], e2 = row[128 + lane], e3 = row[192 + lane];
        acc.x += w.x * e0.x + w.y * e1.x + w.z * e2.x + w.w * e3.x;
        acc.y += w.x * e0.y + w.y * e1.y + w.z * e2.y + w.w * e3.y;
    }
    ((float2*)out)[node * 64 + lane] = acc;
}

// ---------------- final bias+relu, node embeddings, pooled run-atomics ------
// one wave per 16 consecutive nodes (batch is sorted -> few graph switches)
__global__ __launch_bounds__(TPB) void k_final_pool(const float* __restrict__ acc,
                                                    const float* __restrict__ gat_b,
                                                    const int* __restrict__ batch,
                                                    float* __restrict__ node_out,
                                                    float* __restrict__ mean_acc,
                                                    float* __restrict__ max_acc,
                                                    float* __restrict__ cnt, int n) {
    int wave = (blockIdx.x * TPB + threadIdx.x) >> 6;
    int lane = threadIdx.x & 63;
    int n0 = wave * 16;
    if (n0 >= n) return;
    int n1 = min(n0 + 16, n);
    float2 bv = ((const float2*)gat_b)[lane];
    float2 bsum = make_float2(0.f, 0.f), bmax = make_float2(0.f, 0.f);
    int cur_g = batch[n0];
    int cntloc = 0;
    for (int nn = n0; nn < n1; ++nn) {
        int g = batch[nn];
        if (g != cur_g) {
            float* ma = mean_acc + cur_g * 128 + lane * 2;
            atomicAdd(ma + 0, bsum.x);
            atomicAdd(ma + 1, bsum.y);
            int* mxp = (int*)(max_acc + cur_g * 128 + lane * 2);
            atomicMax(mxp + 0, __float_as_int(bmax.x));
            atomicMax(mxp + 1, __float_as_int(bmax.y));
            if (lane == 0) atomicAdd(&cnt[cur_g], (float)cntloc);
            bsum = make_float2(0.f, 0.f);
            bmax = make_float2(0.f, 0.f);
            cntloc = 0;
            cur_g = g;
        }
        float2 a = ((const float2*)acc)[nn * 64 + lane];
        float2 o = make_float2(fmaxf(a.x + bv.x, 0.f), fmaxf(a.y + bv.y, 0.f));
        ((float2*)node_out)[nn * 64 + lane] = o;
        bsum.x += o.x; bsum.y += o.y;
        bmax.x = fmaxf(bmax.x, o.x); bmax.y = fmaxf(bmax.y, o.y);
        ++cntloc;
    }
    float* ma = mean_acc + cur_g * 128 + lane * 2;
    atomicAdd(ma + 0, bsum.x);
    atomicAdd(ma + 1, bsum.y);
    int* mxp = (int*)(max_acc + cur_g * 128 + lane * 2);
    atomicMax(mxp + 0, __float_as_int(bmax.x));
    atomicMax(mxp + 1, __float_as_int(bmax.y));
    if (lane == 0) atomicAdd(&cnt[cur_g], (float)cntloc);
}

__global__ __launch_bounds__(TPB) void k_pool_final(const float* __restrict__ mean_acc,
                                                    const float* __restrict__ max_acc,
                                                    const float* __restrict__ cnt,
                                                    float* __restrict__ gout, int g128) {
    int i = blockIdx.x * TPB + threadIdx.x;
    if (i >= g128) return;
    int g = i >> 7, d = i & 127;
    float c = fmaxf(cnt[g], 1.f);
    gout[g * 256 + d] = mean_acc[i] / c;
    gout[g * 256 + 128 + d] = max_acc[i];
}

// ---------------------------------------------------------------------------
extern "C" void kernel_launch(void* const* d_in, const int* in_sizes, int n_in,
                              void* d_out, int out_size, void* d_ws, size_t ws_size,
                              hipStream_t stream) {
    const float* x       = (const float*)d_in[0];
    const int*   ei      = (const int*)d_in[1];
    const int*   batch   = (const int*)d_in[2];
    const float* W1      = (const float*)d_in[3];
    const float* b1      = (const float*)d_in[4];
    const float* g1      = (const float*)d_in[5];
    const float* beta1   = (const float*)d_in[6];
    const float* W2      = (const float*)d_in[7];
    const float* b2      = (const float*)d_in[8];
    const float* g2      = (const float*)d_in[9];
    const float* beta2   = (const float*)d_in[10];
    const float* gat_W   = (const float*)d_in[11];
    const float* att_src = (const float*)d_in[12];
    const float* att_dst = (const float*)d_in[13];
    const float* gat_b   = (const float*)d_in[14];

    const int N = in_sizes[0] / 128;
    const int E = in_sizes[1] / 2;
    const int G = (out_size - N * 128) / 256;
    const int* src = ei;
    const int* dst = ei + E;

    float* ws = (float*)d_ws;
    float* dis      = ws; ws += N;
    float* A        = ws; ws += (size_t)N * 128;   // gemm out / gat accumulator
    float* B        = ws; ws += (size_t)N * 128;   // h1
    float* C        = ws; ws += (size_t)N * 128;   // h2 (GCN output)
    float* hg       = ws; ws += (size_t)N * 512;   // GAT transformed features
    float* a_s      = ws; ws += N * 4;
    float* a_d      = ws; ws += N * 4;
    float* mean_acc = ws; ws += G * 128;
    float* max_acc  = ws; ws += G * 128;
    float* cnt      = ws; ws += G;
    int* deg       = (int*)ws; ws += N;
    int* row_start = (int*)ws; ws += N + 1;
    int* cursor    = (int*)ws; ws += N + 1;
    int* csr_src   = (int*)ws; ws += E;

    float* gout = (float*)d_out;        // [G, 256]
    float* node_out = gout + G * 256;   // [N, 128]

    auto cdiv = [](long a, long b) { return (int)((a + b - 1) / b); };

    // CSR build (by dst) + degrees
    hipMemsetAsync(deg, 0, (size_t)N * 4, stream);
    k_hist<<<cdiv(E, TPB), TPB, 0, stream>>>(dst, deg, E);
    k_scan<<<1, 1024, 0, stream>>>(deg, row_start, cursor, dis, N, E);
    k_scatter<<<cdiv(E, TPB), TPB, 0, stream>>>(src, dst, cursor, csr_src, E);

    // GCN layer 1
    k_gemm<<<dim3(cdiv(N, 32), 1), TPB, 0, stream>>>(x, W1, A, N, 128);
    k_gcn_fused<<<cdiv((long)N * 64, TPB), TPB, 0, stream>>>(A, csr_src, row_start, dis,
                                                             b1, g1, beta1, B, N);
    // GCN layer 2
    k_gemm<<<dim3(cdiv(N, 32), 1), TPB, 0, stream>>>(B, W2, A, N, 128);
    k_gcn_fused<<<cdiv((long)N * 64, TPB), TPB, 0, stream>>>(A, csr_src, row_start, dis,
                                                             b2, g2, beta2, C, N);
    // GAT
    k_gemm<<<dim3(cdiv(N, 32), 4), TPB, 0, stream>>>(C, gat_W, hg, N, 512);
    k_att_dots<<<cdiv((long)N * 64, TPB), TPB, 0, stream>>>(hg, att_src, att_dst, a_s, a_d, N);
    k_gat_fused<<<cdiv((long)N * 64, TPB), TPB, 0, stream>>>(hg, a_s, a_d, csr_src, row_start, A, N);

    // final + pooling
    hipMemsetAsync(mean_acc, 0, (size_t)(G * 256 + G) * 4, stream);
    k_final_pool<<<cdiv((long)cdiv(N, 16) * 64, TPB), TPB, 0, stream>>>(A, gat_b, batch, node_out,
                                                                        mean_acc, max_acc, cnt, N);
    k_pool_final<<<cdiv((long)G * 128, TPB), TPB, 0, stream>>>(mean_acc, max_acc, cnt, gout, G * 128);
}

// Round 3
// 884.453 us; speedup vs baseline: 5.1184x; 1.5999x over previous
//
#include <hip/hip_runtime.h>
#include <math.h>

// ---------------------------------------------------------------------------
// HOGGraphNet: 2x GCNConv(+LN+ReLU) -> GATConv(4 heads, mean) -> mean/max pool
// N=50000, E=600000, D=128, H=4, G=64. fp32. CSR gather-side aggregation.
// GEMM: LDS-staged W tile, register-blocked 64x128 per block.
// ---------------------------------------------------------------------------

#define TPB 256

__device__ __forceinline__ float lrelu(float x) { return x > 0.f ? x : 0.2f * x; }

// ---------------- CSR build ----------------
__global__ __launch_bounds__(TPB) void k_hist(const int* __restrict__ dst,
                                              int* __restrict__ deg, int e) {
    int i = blockIdx.x * TPB + threadIdx.x;
    if (i < e) atomicAdd(&deg[dst[i]], 1);
}

__global__ __launch_bounds__(1024) void k_scan(const int* __restrict__ deg,
                                               int* __restrict__ row_start,
                                               int* __restrict__ cursor,
                                               float* __restrict__ dis,
                                               int n, int e_total) {
    __shared__ int sm[1024];
    int t = threadIdx.x;
    int chunk = (n + 1023) >> 10;
    int lo = t * chunk, hi = min(lo + chunk, n);
    int s = 0;
    for (int i = lo; i < hi; ++i) s += deg[i];
    sm[t] = s;
    __syncthreads();
    for (int off = 1; off < 1024; off <<= 1) {
        int v = 0;
        if (t >= off) v = sm[t - off];
        __syncthreads();
        if (t >= off) sm[t] += v;
        __syncthreads();
    }
    int run = (t == 0) ? 0 : sm[t - 1];
    for (int i = lo; i < hi; ++i) {
        int d = deg[i];
        row_start[i] = run;
        cursor[i] = run;
        dis[i] = rsqrtf((float)(d + 1));  // +1 self loop
        run += d;
    }
    if (t == 0) row_start[n] = e_total;
}

__global__ __launch_bounds__(TPB) void k_scatter(const int* __restrict__ src,
                                                 const int* __restrict__ dst,
                                                 int* __restrict__ cursor,
                                                 int* __restrict__ csr_src, int e) {
    int i = blockIdx.x * TPB + threadIdx.x;
    if (i < e) {
        int p = atomicAdd(&cursor[dst[i]], 1);
        csr_src[p] = src[i];
    }
}

// ---------------- GEMM: C = A(nrows x 128) * W(128 x ocols) -----------------
// block: 64 rows x 128 cols. W col-slice (128x128 = 64KB) staged in LDS.
// thread (cq=t&31, ro=t>>5) computes rows {ro+8r} x cols cq*4..cq*4+3.
// 2 blocks/CU (64KB LDS each); 32 independent acc chains -> VALU-bound.
__global__ __launch_bounds__(TPB, 2) void k_gemm(const float* __restrict__ A,
                                                 const float* __restrict__ W,
                                                 float* __restrict__ C,
                                                 int nrows, int ocols) {
    __shared__ float4 wl[128 * 32];  // [k][colquad], 64 KB
    int t = threadIdx.x;
    int cq = t & 31, ro = t >> 5;
    int wq = ocols >> 2;
    int cbase4 = blockIdx.y << 5;    // col-quad base of this 128-col tile
    const float4* W4 = (const float4*)W;
    // stage W[0:128][tile]: idx = i*256 + t -> consecutive lanes, consecutive
    // float4s (coalesced global, conflict-free ds_write_b128)
#pragma unroll
    for (int i = 0; i < 16; ++i) {
        int idx = i * 256 + t;       // 0..4095
        int k = idx >> 5, c = idx & 31;
        wl[idx] = W4[k * wq + cbase4 + c];
    }
    __syncthreads();

    int rowbase = blockIdx.x << 6;
    const float4* A4 = (const float4*)A;
    const float4* arow[8];
#pragma unroll
    for (int r = 0; r < 8; ++r) {
        int row = rowbase + ro + 8 * r;
        int rowc = row < nrows ? row : (nrows - 1);  // clamp loads, guard stores
        arow[r] = A4 + (size_t)rowc * 32;
    }
    float4 acc[8];
#pragma unroll
    for (int r = 0; r < 8; ++r) acc[r] = make_float4(0.f, 0.f, 0.f, 0.f);

    for (int k4 = 0; k4 < 32; ++k4) {
        float4 w0 = wl[(k4 * 4 + 0) * 32 + cq];
        float4 w1 = wl[(k4 * 4 + 1) * 32 + cq];
        float4 w2 = wl[(k4 * 4 + 2) * 32 + cq];
        float4 w3 = wl[(k4 * 4 + 3) * 32 + cq];
#pragma unroll
        for (int r = 0; r < 8; ++r) {
            float4 av = arow[r][k4];
            acc[r].x += av.x * w0.x + av.y * w1.x + av.z * w2.x + av.w * w3.x;
            acc[r].y += av.x * w0.y + av.y * w1.y + av.z * w2.y + av.w * w3.y;
            acc[r].z += av.x * w0.z + av.y * w1.z + av.z * w2.z + av.w * w3.z;
            acc[r].w += av.x * w0.w + av.y * w1.w + av.z * w2.w + av.w * w3.w;
        }
    }
    float4* C4 = (float4*)C;
#pragma unroll
    for (int r = 0; r < 8; ++r) {
        int row = rowbase + ro + 8 * r;
        if (row < nrows) C4[(size_t)row * wq + cbase4 + cq] = acc[r];
    }
}

// ---------------- fused GCN: gather + self + bias + LN + ReLU ---------------
__global__ __launch_bounds__(TPB) void k_gcn_fused(const float* __restrict__ h,
                                                   const int* __restrict__ csr_src,
                                                   const int* __restrict__ row_start,
                                                   const float* __restrict__ dis,
                                                   const float* __restrict__ b,
                                                   const float* __restrict__ g,
                                                   const float* __restrict__ beta,
                                                   float* __restrict__ out, int n) {
    int node = (blockIdx.x * TPB + threadIdx.x) >> 6;
    int lane = threadIdx.x & 63;
    if (node >= n) return;
    int s0 = row_start[node], s1 = row_start[node + 1];
    float dn = dis[node];
    const float2* h2 = (const float2*)h;
    float2 acc = make_float2(0.f, 0.f);
    for (int i = s0; i < s1; ++i) {
        int s = csr_src[i];
        float w = dis[s];
        float2 hv = h2[s * 64 + lane];
        acc.x += w * hv.x;
        acc.y += w * hv.y;
    }
    float sl = dn * dn;
    float2 hv = h2[node * 64 + lane];
    float2 bv = ((const float2*)b)[lane];
    float vx = dn * acc.x + sl * hv.x + bv.x;
    float vy = dn * acc.y + sl * hv.y + bv.y;
    float s = vx + vy, sq = vx * vx + vy * vy;
#pragma unroll
    for (int o = 32; o > 0; o >>= 1) {
        s  += __shfl_xor(s, o);
        sq += __shfl_xor(sq, o);
    }
    float mu = s * (1.f / 128.f);
    float var = sq * (1.f / 128.f) - mu * mu;
    float rstd = rsqrtf(var + 1e-5f);
    float2 gv  = ((const float2*)g)[lane];
    float2 btv = ((const float2*)beta)[lane];
    float ox = fmaxf((vx - mu) * rstd * gv.x + btv.x, 0.f);
    float oy = fmaxf((vy - mu) * rstd * gv.y + btv.y, 0.f);
    ((float2*)(out + node * 128))[lane] = make_float2(ox, oy);
}

// ---------------- GAT attention dots ----------------------------------------
__global__ __launch_bounds__(TPB) void k_att_dots(const float* __restrict__ hg,
                                                  const float* __restrict__ att_s,
                                                  const float* __restrict__ att_d,
                                                  float* __restrict__ a_s,
                                                  float* __restrict__ a_d, int n) {
    int wave = (blockIdx.x * TPB + threadIdx.x) >> 6;
    int lane = threadIdx.x & 63;
    if (wave >= n) return;
    int h = lane >> 4, j = lane & 15;
    const float4* hv4 = (const float4*)(hg + (size_t)wave * 512 + h * 128 + j * 8);
    const float4* s4  = (const float4*)(att_s + h * 128 + j * 8);
    const float4* d4  = (const float4*)(att_d + h * 128 + j * 8);
    float4 h0 = hv4[0], h1 = hv4[1];
    float4 s0 = s4[0], s1 = s4[1];
    float4 d0 = d4[0], d1 = d4[1];
    float ps = h0.x * s0.x + h0.y * s0.y + h0.z * s0.z + h0.w * s0.w
             + h1.x * s1.x + h1.y * s1.y + h1.z * s1.z + h1.w * s1.w;
    float pd = h0.x * d0.x + h0.y * d0.y + h0.z * d0.z + h0.w * d0.w
             + h1.x * d1.x + h1.y * d1.y + h1.z * d1.z + h1.w * d1.w;
#pragma unroll
    for (int o = 8; o > 0; o >>= 1) {
        ps += __shfl_xor(ps, o);
        pd += __shfl_xor(pd, o);
    }
    if (j == 0) {
        a_s[wave * 4 + h] = ps;
        a_d[wave * 4 + h] = pd;
    }
}

// ---------------- fused GAT: segment softmax + weighted gather + head mean --
__global__ __launch_bounds__(TPB) void k_gat_fused(const float* __restrict__ hg,
                                                   const float* __restrict__ a_s,
                                                   const float* __restrict__ a_d,
                                                   const int* __restrict__ csr_src,
                                                   const int* __restrict__ row_start,
                                                   float* __restrict__ out, int n) {
    int node = (blockIdx.x * TPB + threadIdx.x) >> 6;
    int lane = threadIdx.x & 63;
    if (node >= n) return;
    int s0 = row_start[node], s1 = row_start[node + 1];
    const float4* as4 = (const float4*)a_s;
    float4 ad = ((const float4*)a_d)[node];
    float4 asn = as4[node];
    float4 selfv;
    selfv.x = lrelu(asn.x + ad.x);
    selfv.y = lrelu(asn.y + ad.y);
    selfv.z = lrelu(asn.z + ad.z);
    selfv.w = lrelu(asn.w + ad.w);
    float4 mx = selfv;
    for (int i = s0 + lane; i < s1; i += 64) {
        int s = csr_src[i];
        float4 a = as4[s];
        mx.x = fmaxf(mx.x, lrelu(a.x + ad.x));
        mx.y = fmaxf(mx.y, lrelu(a.y + ad.y));
        mx.z = fmaxf(mx.z, lrelu(a.z + ad.z));
        mx.w = fmaxf(mx.w, lrelu(a.w + ad.w));
    }
#pragma unroll
    for (int o = 32; o > 0; o >>= 1) {
        mx.x = fmaxf(mx.x, __shfl_xor(mx.x, o));
        mx.y = fmaxf(mx.y, __shfl_xor(mx.y, o));
        mx.z = fmaxf(mx.z, __shfl_xor(mx.z, o));
        mx.w = fmaxf(mx.w, __shfl_xor(mx.w, o));
    }
    float4 den = make_float4(0.f, 0.f, 0.f, 0.f);
    for (int i = s0 + lane; i < s1; i += 64) {
        int s = csr_src[i];
        float4 a = as4[s];
        den.x += __expf(lrelu(a.x + ad.x) - mx.x);
        den.y += __expf(lrelu(a.y + ad.y) - mx.y);
        den.z += __expf(lrelu(a.z + ad.z) - mx.z);
        den.w += __expf(lrelu(a.w + ad.w) - mx.w);
    }
#pragma unroll
    for (int o = 32; o > 0; o >>= 1) {
        den.x += __shfl_xor(den.x, o);
        den.y += __shfl_xor(den.y, o);
        den.z += __shfl_xor(den.z, o);
        den.w += __shfl_xor(den.w, o);
    }
    float4 ws;
    ws.x = __expf(selfv.x - mx.x);
    ws.y = __expf(selfv.y - mx.y);
    ws.z = __expf(selfv.z - mx.z);
    ws.w = __expf(selfv.w - mx.w);
    den.x += ws.x; den.y += ws.y; den.z += ws.z; den.w += ws.w;
    float4 winv;
    winv.x = 0.25f / den.x;
    winv.y = 0.25f / den.y;
    winv.z = 0.25f / den.z;
    winv.w = 0.25f / den.w;
    const float2* hg2 = (const float2*)hg;
    float2 acc;
    {
        float4 w = make_float4(ws.x * winv.x, ws.y * winv.y, ws.z * winv.z, ws.w * winv.w);
        const float2* row = hg2 + (size_t)node * 256;
        float2 e0 = row[lane], e1 = row[64 + lane], e2 = row[128 + lane], e3 = row[192 + lane];
        acc.x = w.x * e0.x + w.y * e1.x + w.z * e2.x + w.w * e3.x;
        acc.y = w.x * e0.y + w.y * e1.y + w.z * e2.y + w.w * e3.y;
    }
    for (int i = s0; i < s1; ++i) {
        int s = csr_src[i];
        float4 a = as4[s];
        float4 w;
        w.x = __expf(lrelu(a.x + ad.x) - mx.x) * winv.x;
        w.y = __expf(lrelu(a.y + ad.y) - mx.y) * winv.y;
        w.z = __expf(lrelu(a.z + ad.z) - mx.z) * winv.z;
        w.w = __expf(lrelu(a.w + ad.w) - mx.w) * winv.w;
        const float2* row = hg2 + (size_t)s * 256;
        float2 e0 = row[lane], e1 = row[64 + lane], e2 = row[128 + lane], e3 = row[192 + lane];
        acc.x += w.x * e0.x + w.y * e1.x + w.z * e2.x + w.w * e3.x;
        acc.y += w.x * e0.y + w.y * e1.y + w.z * e2.y + w.w * e3.y;
    }
    ((float2*)out)[node * 64 + lane] = acc;
}

// ---------------- final bias+relu, node embeddings, pooled run-atomics ------
__global__ __launch_bounds__(TPB) void k_final_pool(const float* __restrict__ acc,
                                                    const float* __restrict__ gat_b,
                                                    const int* __restrict__ batch,
                                                    float* __restrict__ node_out,
                                                    float* __restrict__ mean_acc,
                                                    float* __restrict__ max_acc,
                                                    float* __restrict__ cnt, int n) {
    int wave = (blockIdx.x * TPB + threadIdx.x) >> 6;
    int lane = threadIdx.x & 63;
    int n0 = wave * 16;
    if (n0 >= n) return;
    int n1 = min(n0 + 16, n);
    float2 bv = ((const float2*)gat_b)[lane];
    float2 bsum = make_float2(0.f, 0.f), bmax = make_float2(0.f, 0.f);
    int cur_g = batch[n0];
    int cntloc = 0;
    for (int nn = n0; nn < n1; ++nn) {
        int g = batch[nn];
        if (g != cur_g) {
            float* ma = mean_acc + cur_g * 128 + lane * 2;
            atomicAdd(ma + 0, bsum.x);
            atomicAdd(ma + 1, bsum.y);
            int* mxp = (int*)(max_acc + cur_g * 128 + lane * 2);
            atomicMax(mxp + 0, __float_as_int(bmax.x));
            atomicMax(mxp + 1, __float_as_int(bmax.y));
            if (lane == 0) atomicAdd(&cnt[cur_g], (float)cntloc);
            bsum = make_float2(0.f, 0.f);
            bmax = make_float2(0.f, 0.f);
            cntloc = 0;
            cur_g = g;
        }
        float2 a = ((const float2*)acc)[nn * 64 + lane];
        float2 o = make_float2(fmaxf(a.x + bv.x, 0.f), fmaxf(a.y + bv.y, 0.f));
        ((float2*)node_out)[nn * 64 + lane] = o;
        bsum.x += o.x; bsum.y += o.y;
        bmax.x = fmaxf(bmax.x, o.x); bmax.y = fmaxf(bmax.y, o.y);
        ++cntloc;
    }
    float* ma = mean_acc + cur_g * 128 + lane * 2;
    atomicAdd(ma + 0, bsum.x);
    atomicAdd(ma + 1, bsum.y);
    int* mxp = (int*)(max_acc + cur_g * 128 + lane * 2);
    atomicMax(mxp + 0, __float_as_int(bmax.x));
    atomicMax(mxp + 1, __float_as_int(bmax.y));
    if (lane == 0) atomicAdd(&cnt[cur_g], (float)cntloc);
}

__global__ __launch_bounds__(TPB) void k_pool_final(const float* __restrict__ mean_acc,
                                                    const float* __restrict__ max_acc,
                                                    const float* __restrict__ cnt,
                                                    float* __restrict__ gout, int g128) {
    int i = blockIdx.x * TPB + threadIdx.x;
    if (i >= g128) return;
    int g = i >> 7, d = i & 127;
    float c = fmaxf(cnt[g], 1.f);
    gout[g * 256 + d] = mean_acc[i] / c;
    gout[g * 256 + 128 + d] = max_acc[i];
}

// ---------------------------------------------------------------------------
extern "C" void kernel_launch(void* const* d_in, const int* in_sizes, int n_in,
                              void* d_out, int out_size, void* d_ws, size_t ws_size,
                              hipStream_t stream) {
    const float* x       = (const float*)d_in[0];
    const int*   ei      = (const int*)d_in[1];
    const int*   batch   = (const int*)d_in[2];
    const float* W1      = (const float*)d_in[3];
    const float* b1      = (const float*)d_in[4];
    const float* g1      = (const float*)d_in[5];
    const float* beta1   = (const float*)d_in[6];
    const float* W2      = (const float*)d_in[7];
    const float* b2      = (const float*)d_in[8];
    const float* g2      = (const float*)d_in[9];
    const float* beta2   = (const float*)d_in[10];
    const float* gat_W   = (const float*)d_in[11];
    const float* att_src = (const float*)d_in[12];
    const float* att_dst = (const float*)d_in[13];
    const float* gat_b   = (const float*)d_in[14];

    const int N = in_sizes[0] / 128;
    const int E = in_sizes[1] / 2;
    const int G = (out_size - N * 128) / 256;
    const int* src = ei;
    const int* dst = ei + E;

    float* ws = (float*)d_ws;
    float* dis      = ws; ws += N;
    float* A        = ws; ws += (size_t)N * 128;
    float* B        = ws; ws += (size_t)N * 128;
    float* C        = ws; ws += (size_t)N * 128;
    float* hg       = ws; ws += (size_t)N * 512;
    float* a_s      = ws; ws += N * 4;
    float* a_d      = ws; ws += N * 4;
    float* mean_acc = ws; ws += G * 128;
    float* max_acc  = ws; ws += G * 128;
    float* cnt      = ws; ws += G;
    int* deg       = (int*)ws; ws += N;
    int* row_start = (int*)ws; ws += N + 1;
    int* cursor    = (int*)ws; ws += N + 1;
    int* csr_src   = (int*)ws; ws += E;

    float* gout = (float*)d_out;        // [G, 256]
    float* node_out = gout + G * 256;   // [N, 128]

    auto cdiv = [](long a, long b) { return (int)((a + b - 1) / b); };

    // CSR build (by dst) + degrees
    hipMemsetAsync(deg, 0, (size_t)N * 4, stream);
    k_hist<<<cdiv(E, TPB), TPB, 0, stream>>>(dst, deg, E);
    k_scan<<<1, 1024, 0, stream>>>(deg, row_start, cursor, dis, N, E);
    k_scatter<<<cdiv(E, TPB), TPB, 0, stream>>>(src, dst, cursor, csr_src, E);

    // GCN layer 1
    k_gemm<<<dim3(cdiv(N, 64), 1), TPB, 0, stream>>>(x, W1, A, N, 128);
    k_gcn_fused<<<cdiv((long)N * 64, TPB), TPB, 0, stream>>>(A, csr_src, row_start, dis,
                                                             b1, g1, beta1, B, N);
    // GCN layer 2
    k_gemm<<<dim3(cdiv(N, 64), 1), TPB, 0, stream>>>(B, W2, A, N, 128);
    k_gcn_fused<<<cdiv((long)N * 64, TPB), TPB, 0, stream>>>(A, csr_src, row_start, dis,
                                                             b2, g2, beta2, C, N);
    // GAT
    k_gemm<<<dim3(cdiv(N, 64), 4), TPB, 0, stream>>>(C, gat_W, hg, N, 512);
    k_att_dots<<<cdiv((long)N * 64, TPB), TPB, 0, stream>>>(hg, att_src, att_dst, a_s, a_d, N);
    k_gat_fused<<<cdiv((long)N * 64, TPB), TPB, 0, stream>>>(hg, a_s, a_d, csr_src, row_start, A, N);

    // final + pooling
    hipMemsetAsync(mean_acc, 0, (size_t)(G * 256 + G) * 4, stream);
    k_final_pool<<<cdiv((long)cdiv(N, 16) * 64, TPB), TPB, 0, stream>>>(A, gat_b, batch, node_out,
                                                                        mean_acc, max_acc, cnt, N);
    k_pool_final<<<cdiv((long)G * 128, TPB), TPB, 0, stream>>>(mean_acc, max_acc, cnt, gout, G * 128);
}

// Round 4
// 699.189 us; speedup vs baseline: 6.4746x; 1.2650x over previous
//
#include <hip/hip_runtime.h>
#include <math.h>

// ---------------------------------------------------------------------------
// HOGGraphNet: 2x GCNConv(+LN+ReLU) -> GATConv(4 heads, mean) -> mean/max pool
// N=50000, E=600000, D=128, H=4, G=64. CSR gather-side aggregation.
// Features staged bf16 (fp32 accumulate); single-pass GAT softmax (logits
// bounded -> max-shift dropped, mathematically identical).
// ---------------------------------------------------------------------------

#define TPB 256

__device__ __forceinline__ float lrelu(float x) { return x > 0.f ? x : 0.2f * x; }

__device__ __forceinline__ unsigned short f2bf(float f) {  // RTNE
    unsigned int u = __float_as_uint(f);
    u += 0x7fffu + ((u >> 16) & 1u);
    return (unsigned short)(u >> 16);
}
__device__ __forceinline__ float2 bf2x(unsigned int u) {   // [lo,hi] bf16 pair
    return make_float2(__uint_as_float(u << 16), __uint_as_float(u & 0xffff0000u));
}
__device__ __forceinline__ float sel4(float4 v, int h) {
    float r = v.x;
    r = (h == 1) ? v.y : r;
    r = (h == 2) ? v.z : r;
    r = (h == 3) ? v.w : r;
    return r;
}

// ---------------- CSR build ----------------
__global__ __launch_bounds__(TPB) void k_hist(const int* __restrict__ dst,
                                              int* __restrict__ deg, int e) {
    int i = blockIdx.x * TPB + threadIdx.x;
    if (i < e) atomicAdd(&deg[dst[i]], 1);
}

__global__ __launch_bounds__(1024) void k_scan(const int* __restrict__ deg,
                                               int* __restrict__ row_start,
                                               int* __restrict__ cursor,
                                               float* __restrict__ dis,
                                               int n, int e_total) {
    __shared__ int sm[1024];
    int t = threadIdx.x;
    int chunk = (n + 1023) >> 10;
    int lo = t * chunk, hi = min(lo + chunk, n);
    int s = 0;
    for (int i = lo; i < hi; ++i) s += deg[i];
    sm[t] = s;
    __syncthreads();
    for (int off = 1; off < 1024; off <<= 1) {
        int v = 0;
        if (t >= off) v = sm[t - off];
        __syncthreads();
        if (t >= off) sm[t] += v;
        __syncthreads();
    }
    int run = (t == 0) ? 0 : sm[t - 1];
    for (int i = lo; i < hi; ++i) {
        int d = deg[i];
        row_start[i] = run;
        cursor[i] = run;
        dis[i] = rsqrtf((float)(d + 1));  // +1 self loop
        run += d;
    }
    if (t == 0) row_start[n] = e_total;
}

__global__ __launch_bounds__(TPB) void k_scatter(const int* __restrict__ src,
                                                 const int* __restrict__ dst,
                                                 int* __restrict__ cursor,
                                                 int* __restrict__ csr_src, int e) {
    int i = blockIdx.x * TPB + threadIdx.x;
    if (i < e) {
        int p = atomicAdd(&cursor[dst[i]], 1);
        csr_src[p] = src[i];
    }
}

// ---------------- GEMM: C_bf16 = A(nrows x 128) * W(128 x ocols) ------------
// 64 rows x 128 cols per block; W col-slice (64KB) in LDS; 8x4 regs/thread.
__global__ __launch_bounds__(TPB, 2) void k_gemm_bf(const float* __restrict__ A,
                                                    const float* __restrict__ W,
                                                    unsigned short* __restrict__ C,
                                                    int nrows, int ocols) {
    __shared__ float4 wl[128 * 32];  // [k][colquad], 64 KB
    int t = threadIdx.x;
    int cq = t & 31, ro = t >> 5;
    int wq = ocols >> 2;             // quads per row
    int cbase4 = blockIdx.y << 5;
    const float4* W4 = (const float4*)W;
#pragma unroll
    for (int i = 0; i < 16; ++i) {
        int idx = i * 256 + t;
        int k = idx >> 5, c = idx & 31;
        wl[idx] = W4[k * wq + cbase4 + c];
    }
    __syncthreads();

    int rowbase = blockIdx.x << 6;
    const float4* A4 = (const float4*)A;
    const float4* arow[8];
#pragma unroll
    for (int r = 0; r < 8; ++r) {
        int row = rowbase + ro + 8 * r;
        int rowc = row < nrows ? row : (nrows - 1);
        arow[r] = A4 + (size_t)rowc * 32;
    }
    float4 acc[8];
#pragma unroll
    for (int r = 0; r < 8; ++r) acc[r] = make_float4(0.f, 0.f, 0.f, 0.f);

    for (int k4 = 0; k4 < 32; ++k4) {
        float4 w0 = wl[(k4 * 4 + 0) * 32 + cq];
        float4 w1 = wl[(k4 * 4 + 1) * 32 + cq];
        float4 w2 = wl[(k4 * 4 + 2) * 32 + cq];
        float4 w3 = wl[(k4 * 4 + 3) * 32 + cq];
#pragma unroll
        for (int r = 0; r < 8; ++r) {
            float4 av = arow[r][k4];
            acc[r].x += av.x * w0.x + av.y * w1.x + av.z * w2.x + av.w * w3.x;
            acc[r].y += av.x * w0.y + av.y * w1.y + av.z * w2.y + av.w * w3.y;
            acc[r].z += av.x * w0.z + av.y * w1.z + av.z * w2.z + av.w * w3.z;
            acc[r].w += av.x * w0.w + av.y * w1.w + av.z * w2.w + av.w * w3.w;
        }
    }
    uint2* C2 = (uint2*)C;  // 4 bf16 = 8B per quad
#pragma unroll
    for (int r = 0; r < 8; ++r) {
        int row = rowbase + ro + 8 * r;
        if (row < nrows) {
            unsigned int p0 = (unsigned int)f2bf(acc[r].x) | ((unsigned int)f2bf(acc[r].y) << 16);
            unsigned int p1 = (unsigned int)f2bf(acc[r].z) | ((unsigned int)f2bf(acc[r].w) << 16);
            C2[(size_t)row * wq + cbase4 + cq] = make_uint2(p0, p1);
        }
    }
}

// ---------------- fused GCN: bf16 gather + self + bias + LN + ReLU ----------
// one wave per node, 2 feats/lane; edge weights staged in LDS per 64-chunk
__global__ __launch_bounds__(TPB) void k_gcn_fused(const unsigned short* __restrict__ hb,
                                                   const int* __restrict__ csr_src,
                                                   const int* __restrict__ row_start,
                                                   const float* __restrict__ dis,
                                                   const float* __restrict__ b,
                                                   const float* __restrict__ g,
                                                   const float* __restrict__ beta,
                                                   float* __restrict__ out, int n) {
    __shared__ int   ssrc[4][64];
    __shared__ float swt[4][64];
    int node = (blockIdx.x * TPB + threadIdx.x) >> 6;
    int lane = threadIdx.x & 63;
    int wid = threadIdx.x >> 6;
    if (node >= n) return;
    int s0 = row_start[node], s1 = row_start[node + 1];
    float dn = dis[node];
    const unsigned int* hu = (const unsigned int*)hb;  // 2 bf16 per uint, row=64 uints
    float2 acc = make_float2(0.f, 0.f);
    for (int base = s0; base < s1; base += 64) {
        int cnt = min(64, s1 - base);
        int sidx = 0; float w = 0.f;
        if (lane < cnt) { sidx = csr_src[base + lane]; w = dis[sidx]; }
        ssrc[wid][lane] = sidx;
        swt[wid][lane] = w;
        for (int j = 0; j < cnt; ++j) {
            int s = ssrc[wid][j];
            float wj = swt[wid][j];
            float2 v = bf2x(hu[(size_t)s * 64 + lane]);
            acc.x += wj * v.x;
            acc.y += wj * v.y;
        }
    }
    float sl = dn * dn;
    float2 hv = bf2x(hu[(size_t)node * 64 + lane]);
    float2 bv = ((const float2*)b)[lane];
    float vx = dn * acc.x + sl * hv.x + bv.x;
    float vy = dn * acc.y + sl * hv.y + bv.y;
    float s = vx + vy, sq = vx * vx + vy * vy;
#pragma unroll
    for (int o = 32; o > 0; o >>= 1) {
        s  += __shfl_xor(s, o);
        sq += __shfl_xor(sq, o);
    }
    float mu = s * (1.f / 128.f);
    float var = sq * (1.f / 128.f) - mu * mu;
    float rstd = rsqrtf(var + 1e-5f);
    float2 gv  = ((const float2*)g)[lane];
    float2 btv = ((const float2*)beta)[lane];
    float ox = fmaxf((vx - mu) * rstd * gv.x + btv.x, 0.f);
    float oy = fmaxf((vy - mu) * rstd * gv.y + btv.y, 0.f);
    ((float2*)(out + node * 128))[lane] = make_float2(ox, oy);
}

// ---------------- GAT attention dots (bf16 hg) ------------------------------
__global__ __launch_bounds__(TPB) void k_att_dots(const unsigned short* __restrict__ hgb,
                                                  const float* __restrict__ att_s,
                                                  const float* __restrict__ att_d,
                                                  float* __restrict__ a_s,
                                                  float* __restrict__ a_d, int n) {
    int wave = (blockIdx.x * TPB + threadIdx.x) >> 6;
    int lane = threadIdx.x & 63;
    if (wave >= n) return;
    int h = lane >> 4, j = lane & 15;
    const uint4* hq = (const uint4*)hgb;          // 8 bf16 per uint4, row=64
    uint4 u = hq[(size_t)wave * 64 + lane];       // elems (h*128+j*8)..+7
    float2 p0 = bf2x(u.x), p1 = bf2x(u.y), p2 = bf2x(u.z), p3 = bf2x(u.w);
    const float4* s4 = (const float4*)(att_s + h * 128 + j * 8);
    const float4* d4 = (const float4*)(att_d + h * 128 + j * 8);
    float4 s0 = s4[0], s1 = s4[1];
    float4 d0 = d4[0], d1 = d4[1];
    float ps = p0.x * s0.x + p0.y * s0.y + p1.x * s0.z + p1.y * s0.w
             + p2.x * s1.x + p2.y * s1.y + p3.x * s1.z + p3.y * s1.w;
    float pd = p0.x * d0.x + p0.y * d0.y + p1.x * d0.z + p1.y * d0.w
             + p2.x * d1.x + p2.y * d1.y + p3.x * d1.z + p3.y * d1.w;
#pragma unroll
    for (int o = 8; o > 0; o >>= 1) {
        ps += __shfl_xor(ps, o);
        pd += __shfl_xor(pd, o);
    }
    if (j == 0) {
        a_s[wave * 4 + h] = ps;
        a_d[wave * 4 + h] = pd;
    }
}

// ---------------- fused GAT: single-pass softmax + bf16 gather + head mean --
// logits bounded (|a|<<1) -> exp without max shift == reference softmax.
// wave per node; lane covers head h=lane>>4, features (lane&15)*8..+7.
__global__ __launch_bounds__(TPB) void k_gat_fused(const unsigned short* __restrict__ hgb,
                                                   const float* __restrict__ a_s,
                                                   const float* __restrict__ a_d,
                                                   const int* __restrict__ csr_src,
                                                   const int* __restrict__ row_start,
                                                   float* __restrict__ out, int n) {
    __shared__ int   ssrc[4][64];
    __shared__ float swt[4][4][65];  // [wave][head][edge] +pad: conflict-free
    int node = (blockIdx.x * TPB + threadIdx.x) >> 6;
    int lane = threadIdx.x & 63;
    int wid = threadIdx.x >> 6;
    if (node >= n) return;
    int s0 = row_start[node], s1 = row_start[node + 1];
    int h = lane >> 4;
    const float4* as4 = (const float4*)a_s;
    float4 ad = ((const float4*)a_d)[node];
    float4 asn = as4[node];
    float4 wself;
    wself.x = __expf(lrelu(asn.x + ad.x));
    wself.y = __expf(lrelu(asn.y + ad.y));
    wself.z = __expf(lrelu(asn.z + ad.z));
    wself.w = __expf(lrelu(asn.w + ad.w));
    const uint4* hq = (const uint4*)hgb;  // row = 64 uint4; lane's slice = +lane
    float acc[8];
    {
        float wsh = sel4(wself, h);
        uint4 u = hq[(size_t)node * 64 + lane];
        float2 p0 = bf2x(u.x), p1 = bf2x(u.y), p2 = bf2x(u.z), p3 = bf2x(u.w);
        acc[0] = wsh * p0.x; acc[1] = wsh * p0.y;
        acc[2] = wsh * p1.x; acc[3] = wsh * p1.y;
        acc[4] = wsh * p2.x; acc[5] = wsh * p2.y;
        acc[6] = wsh * p3.x; acc[7] = wsh * p3.y;
    }
    float4 den = make_float4(0.f, 0.f, 0.f, 0.f);  // per-lane partial (excl. self)
    for (int base = s0; base < s1; base += 64) {
        int cnt = min(64, s1 - base);
        int sidx = 0;
        float4 w4 = make_float4(0.f, 0.f, 0.f, 0.f);
        if (lane < cnt) {
            sidx = csr_src[base + lane];
            float4 a = as4[sidx];
            w4.x = __expf(lrelu(a.x + ad.x));
            w4.y = __expf(lrelu(a.y + ad.y));
            w4.z = __expf(lrelu(a.z + ad.z));
            w4.w = __expf(lrelu(a.w + ad.w));
            den.x += w4.x; den.y += w4.y; den.z += w4.z; den.w += w4.w;
        }
        ssrc[wid][lane] = sidx;
        swt[wid][0][lane] = w4.x;
        swt[wid][1][lane] = w4.y;
        swt[wid][2][lane] = w4.z;
        swt[wid][3][lane] = w4.w;
        for (int j = 0; j < cnt; ++j) {
            int s = ssrc[wid][j];
            float wj = swt[wid][h][j];
            uint4 u = hq[(size_t)s * 64 + lane];
            float2 p0 = bf2x(u.x), p1 = bf2x(u.y), p2 = bf2x(u.z), p3 = bf2x(u.w);
            acc[0] += wj * p0.x; acc[1] += wj * p0.y;
            acc[2] += wj * p1.x; acc[3] += wj * p1.y;
            acc[4] += wj * p2.x; acc[5] += wj * p2.y;
            acc[6] += wj * p3.x; acc[7] += wj * p3.y;
        }
    }
    // reduce den across wave, add self
#pragma unroll
    for (int o = 32; o > 0; o >>= 1) {
        den.x += __shfl_xor(den.x, o);
        den.y += __shfl_xor(den.y, o);
        den.z += __shfl_xor(den.z, o);
        den.w += __shfl_xor(den.w, o);
    }
    den.x += wself.x; den.y += wself.y; den.z += wself.z; den.w += wself.w;
    float winv = 0.25f / sel4(den, h);  // folds head mean
#pragma unroll
    for (int j = 0; j < 8; ++j) acc[j] *= winv;
    // head reduce: lanes {l, l+16, l+32, l+48} hold same features, diff heads
#pragma unroll
    for (int j = 0; j < 8; ++j) acc[j] += __shfl_xor(acc[j], 16);
#pragma unroll
    for (int j = 0; j < 8; ++j) acc[j] += __shfl_xor(acc[j], 32);
    if (lane < 16) {
        float4* o4 = (float4*)(out + (size_t)node * 128 + lane * 8);
        o4[0] = make_float4(acc[0], acc[1], acc[2], acc[3]);
        o4[1] = make_float4(acc[4], acc[5], acc[6], acc[7]);
    }
}

// ---------------- final bias+relu, node embeddings, pooled run-atomics ------
__global__ __launch_bounds__(TPB) void k_final_pool(const float* __restrict__ acc,
                                                    const float* __restrict__ gat_b,
                                                    const int* __restrict__ batch,
                                                    float* __restrict__ node_out,
                                                    float* __restrict__ mean_acc,
                                                    float* __restrict__ max_acc,
                                                    float* __restrict__ cnt, int n) {
    int wave = (blockIdx.x * TPB + threadIdx.x) >> 6;
    int lane = threadIdx.x & 63;
    int n0 = wave * 16;
    if (n0 >= n) return;
    int n1 = min(n0 + 16, n);
    float2 bv = ((const float2*)gat_b)[lane];
    float2 bsum = make_float2(0.f, 0.f), bmax = make_float2(0.f, 0.f);
    int cur_g = batch[n0];
    int cntloc = 0;
    for (int nn = n0; nn < n1; ++nn) {
        int g = batch[nn];
        if (g != cur_g) {
            float* ma = mean_acc + cur_g * 128 + lane * 2;
            atomicAdd(ma + 0, bsum.x);
            atomicAdd(ma + 1, bsum.y);
            int* mxp = (int*)(max_acc + cur_g * 128 + lane * 2);
            atomicMax(mxp + 0, __float_as_int(bmax.x));
            atomicMax(mxp + 1, __float_as_int(bmax.y));
            if (lane == 0) atomicAdd(&cnt[cur_g], (float)cntloc);
            bsum = make_float2(0.f, 0.f);
            bmax = make_float2(0.f, 0.f);
            cntloc = 0;
            cur_g = g;
        }
        float2 a = ((const float2*)acc)[nn * 64 + lane];
        float2 o = make_float2(fmaxf(a.x + bv.x, 0.f), fmaxf(a.y + bv.y, 0.f));
        ((float2*)node_out)[nn * 64 + lane] = o;
        bsum.x += o.x; bsum.y += o.y;
        bmax.x = fmaxf(bmax.x, o.x); bmax.y = fmaxf(bmax.y, o.y);
        ++cntloc;
    }
    float* ma = mean_acc + cur_g * 128 + lane * 2;
    atomicAdd(ma + 0, bsum.x);
    atomicAdd(ma + 1, bsum.y);
    int* mxp = (int*)(max_acc + cur_g * 128 + lane * 2);
    atomicMax(mxp + 0, __float_as_int(bmax.x));
    atomicMax(mxp + 1, __float_as_int(bmax.y));
    if (lane == 0) atomicAdd(&cnt[cur_g], (float)cntloc);
}

__global__ __launch_bounds__(TPB) void k_pool_final(const float* __restrict__ mean_acc,
                                                    const float* __restrict__ max_acc,
                                                    const float* __restrict__ cnt,
                                                    float* __restrict__ gout, int g128) {
    int i = blockIdx.x * TPB + threadIdx.x;
    if (i >= g128) return;
    int g = i >> 7, d = i & 127;
    float c = fmaxf(cnt[g], 1.f);
    gout[g * 256 + d] = mean_acc[i] / c;
    gout[g * 256 + 128 + d] = max_acc[i];
}

// ---------------------------------------------------------------------------
extern "C" void kernel_launch(void* const* d_in, const int* in_sizes, int n_in,
                              void* d_out, int out_size, void* d_ws, size_t ws_size,
                              hipStream_t stream) {
    const float* x       = (const float*)d_in[0];
    const int*   ei      = (const int*)d_in[1];
    const int*   batch   = (const int*)d_in[2];
    const float* W1      = (const float*)d_in[3];
    const float* b1      = (const float*)d_in[4];
    const float* g1      = (const float*)d_in[5];
    const float* beta1   = (const float*)d_in[6];
    const float* W2      = (const float*)d_in[7];
    const float* b2      = (const float*)d_in[8];
    const float* g2      = (const float*)d_in[9];
    const float* beta2   = (const float*)d_in[10];
    const float* gat_W   = (const float*)d_in[11];
    const float* att_src = (const float*)d_in[12];
    const float* att_dst = (const float*)d_in[13];
    const float* gat_b   = (const float*)d_in[14];

    const int N = in_sizes[0] / 128;
    const int E = in_sizes[1] / 2;
    const int G = (out_size - N * 128) / 256;
    const int* src = ei;
    const int* dst = ei + E;

    float* ws = (float*)d_ws;
    float* dis      = ws; ws += N;
    float* B        = ws; ws += (size_t)N * 128;   // h1 post-LN / GAT out
    float* C        = ws; ws += (size_t)N * 128;   // h2 post-LN (GAT gemm in)
    float* a_s      = ws; ws += N * 4;
    float* a_d      = ws; ws += N * 4;
    float* mean_acc = ws; ws += G * 128;
    float* max_acc  = ws; ws += G * 128;
    float* cnt      = ws; ws += G;
    unsigned short* Abf = (unsigned short*)ws; ws += (size_t)N * 64;   // [N,128] bf16
    unsigned short* hgb = (unsigned short*)ws; ws += (size_t)N * 256;  // [N,512] bf16
    int* deg       = (int*)ws; ws += N;
    int* row_start = (int*)ws; ws += N + 1;
    int* cursor    = (int*)ws; ws += N + 1;
    int* csr_src   = (int*)ws; ws += E;

    float* gout = (float*)d_out;        // [G, 256]
    float* node_out = gout + G * 256;   // [N, 128]

    auto cdiv = [](long a, long b) { return (int)((a + b - 1) / b); };

    // CSR build (by dst) + degrees
    hipMemsetAsync(deg, 0, (size_t)N * 4, stream);
    k_hist<<<cdiv(E, TPB), TPB, 0, stream>>>(dst, deg, E);
    k_scan<<<1, 1024, 0, stream>>>(deg, row_start, cursor, dis, N, E);
    k_scatter<<<cdiv(E, TPB), TPB, 0, stream>>>(src, dst, cursor, csr_src, E);

    // GCN layer 1
    k_gemm_bf<<<dim3(cdiv(N, 64), 1), TPB, 0, stream>>>(x, W1, Abf, N, 128);
    k_gcn_fused<<<cdiv((long)N * 64, TPB), TPB, 0, stream>>>(Abf, csr_src, row_start, dis,
                                                             b1, g1, beta1, B, N);
    // GCN layer 2
    k_gemm_bf<<<dim3(cdiv(N, 64), 1), TPB, 0, stream>>>(B, W2, Abf, N, 128);
    k_gcn_fused<<<cdiv((long)N * 64, TPB), TPB, 0, stream>>>(Abf, csr_src, row_start, dis,
                                                             b2, g2, beta2, C, N);
    // GAT
    k_gemm_bf<<<dim3(cdiv(N, 64), 4), TPB, 0, stream>>>(C, gat_W, hgb, N, 512);
    k_att_dots<<<cdiv((long)N * 64, TPB), TPB, 0, stream>>>(hgb, att_src, att_dst, a_s, a_d, N);
    k_gat_fused<<<cdiv((long)N * 64, TPB), TPB, 0, stream>>>(hgb, a_s, a_d, csr_src, row_start, B, N);

    // final + pooling
    hipMemsetAsync(mean_acc, 0, (size_t)(G * 256 + G) * 4, stream);
    k_final_pool<<<cdiv((long)cdiv(N, 16) * 64, TPB), TPB, 0, stream>>>(B, gat_b, batch, node_out,
                                                                        mean_acc, max_acc, cnt, N);
    k_pool_final<<<cdiv((long)G * 128, TPB), TPB, 0, stream>>>(mean_acc, max_acc, cnt, gout, G * 128);
}

// Round 5
// 577.631 us; speedup vs baseline: 7.8372x; 1.2104x over previous
//
#include <hip/hip_runtime.h>
#include <math.h>

// ---------------------------------------------------------------------------
// HOGGraphNet: 2x GCNConv(+LN+ReLU) -> GATConv(4 heads, mean) -> mean/max pool
// N=50000, E=600000, D=128, H=4, G=64. CSR gather-side aggregation.
// bf16 feature pipeline; GEMMs on MFMA (16x16x32 bf16, fp32 accumulate).
// ---------------------------------------------------------------------------

#define TPB 256

typedef __attribute__((ext_vector_type(8))) short short8;
typedef __attribute__((ext_vector_type(4))) float f32x4;
union U4S8 { uint4 u; short8 s; };

__device__ __forceinline__ float lrelu(float x) { return x > 0.f ? x : 0.2f * x; }

__device__ __forceinline__ unsigned short f2bf(float f) {  // RTNE
    unsigned int u = __float_as_uint(f);
    u += 0x7fffu + ((u >> 16) & 1u);
    return (unsigned short)(u >> 16);
}
__device__ __forceinline__ float2 bf2x(unsigned int u) {   // [lo,hi] bf16 pair
    return make_float2(__uint_as_float(u << 16), __uint_as_float(u & 0xffff0000u));
}
__device__ __forceinline__ float sel4(float4 v, int h) {
    float r = v.x;
    r = (h == 1) ? v.y : r;
    r = (h == 2) ? v.z : r;
    r = (h == 3) ? v.w : r;
    return r;
}

// ---------------- CSR build ----------------
__global__ __launch_bounds__(TPB) void k_hist(const int* __restrict__ dst,
                                              int* __restrict__ deg, int e) {
    int i = blockIdx.x * TPB + threadIdx.x;
    if (i < e) atomicAdd(&deg[dst[i]], 1);
}

__global__ __launch_bounds__(1024) void k_scan(const int* __restrict__ deg,
                                               int* __restrict__ row_start,
                                               int* __restrict__ cursor,
                                               float* __restrict__ dis,
                                               int n, int e_total) {
    __shared__ int sm[1024];
    int t = threadIdx.x;
    int chunk = (n + 1023) >> 10;
    int lo = t * chunk, hi = min(lo + chunk, n);
    int s = 0;
    for (int i = lo; i < hi; ++i) s += deg[i];
    sm[t] = s;
    __syncthreads();
    for (int off = 1; off < 1024; off <<= 1) {
        int v = 0;
        if (t >= off) v = sm[t - off];
        __syncthreads();
        if (t >= off) sm[t] += v;
        __syncthreads();
    }
    int run = (t == 0) ? 0 : sm[t - 1];
    for (int i = lo; i < hi; ++i) {
        int d = deg[i];
        row_start[i] = run;
        cursor[i] = run;
        dis[i] = rsqrtf((float)(d + 1));  // +1 self loop
        run += d;
    }
    if (t == 0) row_start[n] = e_total;
}

__global__ __launch_bounds__(TPB) void k_scatter(const int* __restrict__ src,
                                                 const int* __restrict__ dst,
                                                 int* __restrict__ cursor,
                                                 int* __restrict__ csr_src, int e) {
    int i = blockIdx.x * TPB + threadIdx.x;
    if (i < e) {
        int p = atomicAdd(&cursor[dst[i]], 1);
        csr_src[p] = src[i];
    }
}

// ---------------- conversions ----------------
// fp32 -> bf16, 4 elems/thread
__global__ __launch_bounds__(TPB) void k_f2bf(const float* __restrict__ in,
                                              unsigned short* __restrict__ out, int n4) {
    int i = blockIdx.x * TPB + threadIdx.x;
    if (i >= n4) return;
    float4 v = ((const float4*)in)[i];
    unsigned int p0 = (unsigned int)f2bf(v.x) | ((unsigned int)f2bf(v.y) << 16);
    unsigned int p1 = (unsigned int)f2bf(v.z) | ((unsigned int)f2bf(v.w) << 16);
    ((uint2*)out)[i] = make_uint2(p0, p1);
}

// W[k][n] fp32 -> Wt[n][k] bf16  (K=128)
__global__ __launch_bounds__(TPB) void k_wt(const float* __restrict__ W,
                                            unsigned short* __restrict__ Wt, int ocols) {
    int i = blockIdx.x * TPB + threadIdx.x;
    if (i >= 128 * ocols) return;
    int k = i / ocols, n = i - k * ocols;   // consecutive threads -> consecutive n
    Wt[n * 128 + k] = f2bf(W[i]);
}

// ---------------- MFMA GEMM: C[node][chan] = feat[node][:] . Wt[chan][:] ----
// A-operand = Wt (LDS, frag-linear), B-operand = features (global, contiguous).
// Block: 256 thr = 4 waves (2x2), tile 128 chan x 128 node, K=128 (4 ksteps).
__global__ __launch_bounds__(TPB, 2) void k_gemm_mfma(const unsigned short* __restrict__ feat,
                                                      const unsigned short* __restrict__ Wt,
                                                      unsigned short* __restrict__ C,
                                                      int nrows, int ocols) {
    __shared__ uint4 wl[2048];  // 32KB: [ks][ct][lane] fragment-linear
    int t = threadIdx.x;
    int cb = blockIdx.y << 7;   // chan base
#pragma unroll
    for (int i = 0; i < 8; ++i) {
        int fi = i * 256 + t;             // 0..2047
        int l = fi & 63, ct = (fi >> 6) & 7, ks = fi >> 9;
        int chan = cb + ct * 16 + (l & 15);
        wl[fi] = ((const uint4*)(Wt + (size_t)chan * 128))[ks * 4 + (l >> 4)];
    }
    __syncthreads();

    int wave = t >> 6, lane = t & 63;
    int wr = wave >> 1, wc = wave & 1;
    int nbase = (blockIdx.x << 7) + (wc << 6);
    const uint4* brow[4];
#pragma unroll
    for (int nt = 0; nt < 4; ++nt) {
        int node = nbase + nt * 16 + (lane & 15);
        node = node < nrows ? node : (nrows - 1);   // clamp loads, guard stores
        brow[nt] = (const uint4*)(feat + (size_t)node * 128);
    }
    f32x4 acc[4][4];
#pragma unroll
    for (int mt = 0; mt < 4; ++mt)
#pragma unroll
        for (int nt = 0; nt < 4; ++nt) acc[mt][nt] = (f32x4)0.f;

    int kq = lane >> 4;  // 16B chunk within kstep
#pragma unroll
    for (int ks = 0; ks < 4; ++ks) {
        U4S8 a[4], b[4];
#pragma unroll
        for (int mt = 0; mt < 4; ++mt)
            a[mt].u = wl[(ks * 8 + wr * 4 + mt) * 64 + lane];
#pragma unroll
        for (int nt = 0; nt < 4; ++nt)
            b[nt].u = brow[nt][ks * 4 + kq];
#pragma unroll
        for (int mt = 0; mt < 4; ++mt)
#pragma unroll
            for (int nt = 0; nt < 4; ++nt)
                acc[mt][nt] = __builtin_amdgcn_mfma_f32_16x16x32_bf16(
                    a[mt].s, b[nt].s, acc[mt][nt], 0, 0, 0);
    }
    // C/D layout: col(node)=lane&15, row(chan)=(lane>>4)*4+reg
#pragma unroll
    for (int nt = 0; nt < 4; ++nt) {
        int node = nbase + nt * 16 + (lane & 15);
        if (node >= nrows) continue;
#pragma unroll
        for (int mt = 0; mt < 4; ++mt) {
            int chan = cb + (wr << 6) + mt * 16 + (lane >> 4) * 4;
            f32x4 v = acc[mt][nt];
            unsigned int p0 = (unsigned int)f2bf(v.x) | ((unsigned int)f2bf(v.y) << 16);
            unsigned int p1 = (unsigned int)f2bf(v.z) | ((unsigned int)f2bf(v.w) << 16);
            *(uint2*)(C + (size_t)node * ocols + chan) = make_uint2(p0, p1);
        }
    }
}

// ---------------- fused GCN: bf16 gather + self + bias + LN + ReLU -> bf16 --
__global__ __launch_bounds__(TPB) void k_gcn_fused(const unsigned short* __restrict__ hb,
                                                   const int* __restrict__ csr_src,
                                                   const int* __restrict__ row_start,
                                                   const float* __restrict__ dis,
                                                   const float* __restrict__ b,
                                                   const float* __restrict__ g,
                                                   const float* __restrict__ beta,
                                                   unsigned short* __restrict__ out, int n) {
    __shared__ int   ssrc[4][64];
    __shared__ float swt[4][64];
    int node = (blockIdx.x * TPB + threadIdx.x) >> 6;
    int lane = threadIdx.x & 63;
    int wid = threadIdx.x >> 6;
    if (node >= n) return;
    int s0 = row_start[node], s1 = row_start[node + 1];
    float dn = dis[node];
    const unsigned int* hu = (const unsigned int*)hb;  // 2 bf16/uint, row=64
    float2 acc = make_float2(0.f, 0.f);
    for (int base = s0; base < s1; base += 64) {
        int cnt = min(64, s1 - base);
        int sidx = 0; float w = 0.f;
        if (lane < cnt) { sidx = csr_src[base + lane]; w = dis[sidx]; }
        ssrc[wid][lane] = sidx;
        swt[wid][lane] = w;
        for (int j = 0; j < cnt; ++j) {
            int s = ssrc[wid][j];
            float wj = swt[wid][j];
            float2 v = bf2x(hu[(size_t)s * 64 + lane]);
            acc.x += wj * v.x;
            acc.y += wj * v.y;
        }
    }
    float sl = dn * dn;
    float2 hv = bf2x(hu[(size_t)node * 64 + lane]);
    float2 bv = ((const float2*)b)[lane];
    float vx = dn * acc.x + sl * hv.x + bv.x;
    float vy = dn * acc.y + sl * hv.y + bv.y;
    float s = vx + vy, sq = vx * vx + vy * vy;
#pragma unroll
    for (int o = 32; o > 0; o >>= 1) {
        s  += __shfl_xor(s, o);
        sq += __shfl_xor(sq, o);
    }
    float mu = s * (1.f / 128.f);
    float var = sq * (1.f / 128.f) - mu * mu;
    float rstd = rsqrtf(var + 1e-5f);
    float2 gv  = ((const float2*)g)[lane];
    float2 btv = ((const float2*)beta)[lane];
    float ox = fmaxf((vx - mu) * rstd * gv.x + btv.x, 0.f);
    float oy = fmaxf((vy - mu) * rstd * gv.y + btv.y, 0.f);
    ((unsigned int*)out)[(size_t)node * 64 + lane] =
        (unsigned int)f2bf(ox) | ((unsigned int)f2bf(oy) << 16);
}

// ---------------- GAT attention dots (bf16 hg) ------------------------------
__global__ __launch_bounds__(TPB) void k_att_dots(const unsigned short* __restrict__ hgb,
                                                  const float* __restrict__ att_s,
                                                  const float* __restrict__ att_d,
                                                  float* __restrict__ a_s,
                                                  float* __restrict__ a_d, int n) {
    int wave = (blockIdx.x * TPB + threadIdx.x) >> 6;
    int lane = threadIdx.x & 63;
    if (wave >= n) return;
    int h = lane >> 4, j = lane & 15;
    const uint4* hq = (const uint4*)hgb;
    uint4 u = hq[(size_t)wave * 64 + lane];
    float2 p0 = bf2x(u.x), p1 = bf2x(u.y), p2 = bf2x(u.z), p3 = bf2x(u.w);
    const float4* s4 = (const float4*)(att_s + h * 128 + j * 8);
    const float4* d4 = (const float4*)(att_d + h * 128 + j * 8);
    float4 s0 = s4[0], s1 = s4[1];
    float4 d0 = d4[0], d1 = d4[1];
    float ps = p0.x * s0.x + p0.y * s0.y + p1.x * s0.z + p1.y * s0.w
             + p2.x * s1.x + p2.y * s1.y + p3.x * s1.z + p3.y * s1.w;
    float pd = p0.x * d0.x + p0.y * d0.y + p1.x * d0.z + p1.y * d0.w
             + p2.x * d1.x + p2.y * d1.y + p3.x * d1.z + p3.y * d1.w;
#pragma unroll
    for (int o = 8; o > 0; o >>= 1) {
        ps += __shfl_xor(ps, o);
        pd += __shfl_xor(pd, o);
    }
    if (j == 0) {
        a_s[wave * 4 + h] = ps;
        a_d[wave * 4 + h] = pd;
    }
}

// ---------------- fused GAT: single-pass softmax + bf16 gather + head mean --
__global__ __launch_bounds__(TPB) void k_gat_fused(const unsigned short* __restrict__ hgb,
                                                   const float* __restrict__ a_s,
                                                   const float* __restrict__ a_d,
                                                   const int* __restrict__ csr_src,
                                                   const int* __restrict__ row_start,
                                                   float* __restrict__ out, int n) {
    __shared__ int   ssrc[4][64];
    __shared__ float swt[4][4][65];
    int node = (blockIdx.x * TPB + threadIdx.x) >> 6;
    int lane = threadIdx.x & 63;
    int wid = threadIdx.x >> 6;
    if (node >= n) return;
    int s0 = row_start[node], s1 = row_start[node + 1];
    int h = lane >> 4;
    const float4* as4 = (const float4*)a_s;
    float4 ad = ((const float4*)a_d)[node];
    float4 asn = as4[node];
    float4 wself;
    wself.x = __expf(lrelu(asn.x + ad.x));
    wself.y = __expf(lrelu(asn.y + ad.y));
    wself.z = __expf(lrelu(asn.z + ad.z));
    wself.w = __expf(lrelu(asn.w + ad.w));
    const uint4* hq = (const uint4*)hgb;
    float acc[8];
    {
        float wsh = sel4(wself, h);
        uint4 u = hq[(size_t)node * 64 + lane];
        float2 p0 = bf2x(u.x), p1 = bf2x(u.y), p2 = bf2x(u.z), p3 = bf2x(u.w);
        acc[0] = wsh * p0.x; acc[1] = wsh * p0.y;
        acc[2] = wsh * p1.x; acc[3] = wsh * p1.y;
        acc[4] = wsh * p2.x; acc[5] = wsh * p2.y;
        acc[6] = wsh * p3.x; acc[7] = wsh * p3.y;
    }
    float4 den = make_float4(0.f, 0.f, 0.f, 0.f);
    for (int base = s0; base < s1; base += 64) {
        int cnt = min(64, s1 - base);
        int sidx = 0;
        float4 w4 = make_float4(0.f, 0.f, 0.f, 0.f);
        if (lane < cnt) {
            sidx = csr_src[base + lane];
            float4 a = as4[sidx];
            w4.x = __expf(lrelu(a.x + ad.x));
            w4.y = __expf(lrelu(a.y + ad.y));
            w4.z = __expf(lrelu(a.z + ad.z));
            w4.w = __expf(lrelu(a.w + ad.w));
            den.x += w4.x; den.y += w4.y; den.z += w4.z; den.w += w4.w;
        }
        ssrc[wid][lane] = sidx;
        swt[wid][0][lane] = w4.x;
        swt[wid][1][lane] = w4.y;
        swt[wid][2][lane] = w4.z;
        swt[wid][3][lane] = w4.w;
        for (int j = 0; j < cnt; ++j) {
            int s = ssrc[wid][j];
            float wj = swt[wid][h][j];
            uint4 u = hq[(size_t)s * 64 + lane];
            float2 p0 = bf2x(u.x), p1 = bf2x(u.y), p2 = bf2x(u.z), p3 = bf2x(u.w);
            acc[0] += wj * p0.x; acc[1] += wj * p0.y;
            acc[2] += wj * p1.x; acc[3] += wj * p1.y;
            acc[4] += wj * p2.x; acc[5] += wj * p2.y;
            acc[6] += wj * p3.x; acc[7] += wj * p3.y;
        }
    }
#pragma unroll
    for (int o = 32; o > 0; o >>= 1) {
        den.x += __shfl_xor(den.x, o);
        den.y += __shfl_xor(den.y, o);
        den.z += __shfl_xor(den.z, o);
        den.w += __shfl_xor(den.w, o);
    }
    den.x += wself.x; den.y += wself.y; den.z += wself.z; den.w += wself.w;
    float winv = 0.25f / sel4(den, h);
#pragma unroll
    for (int j = 0; j < 8; ++j) acc[j] *= winv;
#pragma unroll
    for (int j = 0; j < 8; ++j) acc[j] += __shfl_xor(acc[j], 16);
#pragma unroll
    for (int j = 0; j < 8; ++j) acc[j] += __shfl_xor(acc[j], 32);
    if (lane < 16) {
        float4* o4 = (float4*)(out + (size_t)node * 128 + lane * 8);
        o4[0] = make_float4(acc[0], acc[1], acc[2], acc[3]);
        o4[1] = make_float4(acc[4], acc[5], acc[6], acc[7]);
    }
}

// ---------------- final bias+relu, node embeddings, pooled run-atomics ------
__global__ __launch_bounds__(TPB) void k_final_pool(const float* __restrict__ acc,
                                                    const float* __restrict__ gat_b,
                                                    const int* __restrict__ batch,
                                                    float* __restrict__ node_out,
                                                    float* __restrict__ mean_acc,
                                                    float* __restrict__ max_acc,
                                                    float* __restrict__ cnt, int n) {
    int wave = (blockIdx.x * TPB + threadIdx.x) >> 6;
    int lane = threadIdx.x & 63;
    int n0 = wave * 16;
    if (n0 >= n) return;
    int n1 = min(n0 + 16, n);
    float2 bv = ((const float2*)gat_b)[lane];
    float2 bsum = make_float2(0.f, 0.f), bmax = make_float2(0.f, 0.f);
    int cur_g = batch[n0];
    int cntloc = 0;
    for (int nn = n0; nn < n1; ++nn) {
        int g = batch[nn];
        if (g != cur_g) {
            float* ma = mean_acc + cur_g * 128 + lane * 2;
            atomicAdd(ma + 0, bsum.x);
            atomicAdd(ma + 1, bsum.y);
            int* mxp = (int*)(max_acc + cur_g * 128 + lane * 2);
            atomicMax(mxp + 0, __float_as_int(bmax.x));
            atomicMax(mxp + 1, __float_as_int(bmax.y));
            if (lane == 0) atomicAdd(&cnt[cur_g], (float)cntloc);
            bsum = make_float2(0.f, 0.f);
            bmax = make_float2(0.f, 0.f);
            cntloc = 0;
            cur_g = g;
        }
        float2 a = ((const float2*)acc)[nn * 64 + lane];
        float2 o = make_float2(fmaxf(a.x + bv.x, 0.f), fmaxf(a.y + bv.y, 0.f));
        ((float2*)node_out)[nn * 64 + lane] = o;
        bsum.x += o.x; bsum.y += o.y;
        bmax.x = fmaxf(bmax.x, o.x); bmax.y = fmaxf(bmax.y, o.y);
        ++cntloc;
    }
    float* ma = mean_acc + cur_g * 128 + lane * 2;
    atomicAdd(ma + 0, bsum.x);
    atomicAdd(ma + 1, bsum.y);
    int* mxp = (int*)(max_acc + cur_g * 128 + lane * 2);
    atomicMax(mxp + 0, __float_as_int(bmax.x));
    atomicMax(mxp + 1, __float_as_int(bmax.y));
    if (lane == 0) atomicAdd(&cnt[cur_g], (float)cntloc);
}

__global__ __launch_bounds__(TPB) void k_pool_final(const float* __restrict__ mean_acc,
                                                    const float* __restrict__ max_acc,
                                                    const float* __restrict__ cnt,
                                                    float* __restrict__ gout, int g128) {
    int i = blockIdx.x * TPB + threadIdx.x;
    if (i >= g128) return;
    int g = i >> 7, d = i & 127;
    float c = fmaxf(cnt[g], 1.f);
    gout[g * 256 + d] = mean_acc[i] / c;
    gout[g * 256 + 128 + d] = max_acc[i];
}

// ---------------------------------------------------------------------------
extern "C" void kernel_launch(void* const* d_in, const int* in_sizes, int n_in,
                              void* d_out, int out_size, void* d_ws, size_t ws_size,
                              hipStream_t stream) {
    const float* x       = (const float*)d_in[0];
    const int*   ei      = (const int*)d_in[1];
    const int*   batch   = (const int*)d_in[2];
    const float* W1      = (const float*)d_in[3];
    const float* b1      = (const float*)d_in[4];
    const float* g1      = (const float*)d_in[5];
    const float* beta1   = (const float*)d_in[6];
    const float* W2      = (const float*)d_in[7];
    const float* b2      = (const float*)d_in[8];
    const float* g2      = (const float*)d_in[9];
    const float* beta2   = (const float*)d_in[10];
    const float* gat_W   = (const float*)d_in[11];
    const float* att_src = (const float*)d_in[12];
    const float* att_dst = (const float*)d_in[13];
    const float* gat_b   = (const float*)d_in[14];

    const int N = in_sizes[0] / 128;
    const int E = in_sizes[1] / 2;
    const int G = (out_size - N * 128) / 256;
    const int* src = ei;
    const int* dst = ei + E;

    float* ws = (float*)d_ws;
    float* dis      = ws; ws += N;
    float* Bf       = ws; ws += (size_t)N * 128;   // GAT out (fp32)
    float* a_s      = ws; ws += N * 4;
    float* a_d      = ws; ws += N * 4;
    float* mean_acc = ws; ws += G * 128;
    float* max_acc  = ws; ws += G * 128;
    float* cnt      = ws; ws += G;
    unsigned short* xb  = (unsigned short*)ws; ws += (size_t)N * 64;   // [N,128] bf16
    unsigned short* Hbf = (unsigned short*)ws; ws += (size_t)N * 64;   // GEMM out
    unsigned short* Bbf = (unsigned short*)ws; ws += (size_t)N * 64;   // h1 post-LN
    unsigned short* Cbf = (unsigned short*)ws; ws += (size_t)N * 64;   // h2 post-LN
    unsigned short* hgb = (unsigned short*)ws; ws += (size_t)N * 256;  // [N,512] bf16
    unsigned short* Wt1 = (unsigned short*)ws; ws += 128 * 64;
    unsigned short* Wt2 = (unsigned short*)ws; ws += 128 * 64;
    unsigned short* Wtg = (unsigned short*)ws; ws += 512 * 64;
    int* deg       = (int*)ws; ws += N;
    int* row_start = (int*)ws; ws += N + 1;
    int* cursor    = (int*)ws; ws += N + 1;
    int* csr_src   = (int*)ws; ws += E;

    float* gout = (float*)d_out;        // [G, 256]
    float* node_out = gout + G * 256;   // [N, 128]

    auto cdiv = [](long a, long b) { return (int)((a + b - 1) / b); };

    // CSR build (by dst) + degrees
    hipMemsetAsync(deg, 0, (size_t)N * 4, stream);
    k_hist<<<cdiv(E, TPB), TPB, 0, stream>>>(dst, deg, E);
    k_scan<<<1, 1024, 0, stream>>>(deg, row_start, cursor, dis, N, E);
    k_scatter<<<cdiv(E, TPB), TPB, 0, stream>>>(src, dst, cursor, csr_src, E);

    // conversions
    k_f2bf<<<cdiv((long)N * 32, TPB), TPB, 0, stream>>>(x, xb, N * 32);
    k_wt<<<cdiv(128 * 128, TPB), TPB, 0, stream>>>(W1, Wt1, 128);
    k_wt<<<cdiv(128 * 128, TPB), TPB, 0, stream>>>(W2, Wt2, 128);
    k_wt<<<cdiv(128 * 512, TPB), TPB, 0, stream>>>(gat_W, Wtg, 512);

    // GCN layer 1
    k_gemm_mfma<<<dim3(cdiv(N, 128), 1), TPB, 0, stream>>>(xb, Wt1, Hbf, N, 128);
    k_gcn_fused<<<cdiv((long)N * 64, TPB), TPB, 0, stream>>>(Hbf, csr_src, row_start, dis,
                                                             b1, g1, beta1, Bbf, N);
    // GCN layer 2
    k_gemm_mfma<<<dim3(cdiv(N, 128), 1), TPB, 0, stream>>>(Bbf, Wt2, Hbf, N, 128);
    k_gcn_fused<<<cdiv((long)N * 64, TPB), TPB, 0, stream>>>(Hbf, csr_src, row_start, dis,
                                                             b2, g2, beta2, Cbf, N);
    // GAT
    k_gemm_mfma<<<dim3(cdiv(N, 128), 4), TPB, 0, stream>>>(Cbf, Wtg, hgb, N, 512);
    k_att_dots<<<cdiv((long)N * 64, TPB), TPB, 0, stream>>>(hgb, att_src, att_dst, a_s, a_d, N);
    k_gat_fused<<<cdiv((long)N * 64, TPB), TPB, 0, stream>>>(hgb, a_s, a_d, csr_src, row_start, Bf, N);

    // final + pooling
    hipMemsetAsync(mean_acc, 0, (size_t)(G * 256 + G) * 4, stream);
    k_final_pool<<<cdiv((long)cdiv(N, 16) * 64, TPB), TPB, 0, stream>>>(Bf, gat_b, batch, node_out,
                                                                        mean_acc, max_acc, cnt, N);
    k_pool_final<<<cdiv((long)G * 128, TPB), TPB, 0, stream>>>(mean_acc, max_acc, cnt, gout, G * 128);
}

// Round 6
// 454.656 us; speedup vs baseline: 9.9569x; 1.2705x over previous
//
#include <hip/hip_runtime.h>
#include <math.h>

// ---------------------------------------------------------------------------
// HOGGraphNet: 2x GCNConv(+LN+ReLU) -> GATConv(4 heads, mean) -> mean/max pool
// N=50000, E=600000, D=128, H=4, G=64. CSR gather-side aggregation.
// bf16 feature pipeline; GEMMs on MFMA (16x16x32 bf16, fp32 accumulate).
// CSR prefix scan: 3-kernel parallel (block sums -> top scan -> apply).
// ---------------------------------------------------------------------------

#define TPB 256

typedef __attribute__((ext_vector_type(8))) short short8;
typedef __attribute__((ext_vector_type(4))) float f32x4;
union U4S8 { uint4 u; short8 s; };

__device__ __forceinline__ float lrelu(float x) { return x > 0.f ? x : 0.2f * x; }

__device__ __forceinline__ unsigned short f2bf(float f) {  // RTNE
    unsigned int u = __float_as_uint(f);
    u += 0x7fffu + ((u >> 16) & 1u);
    return (unsigned short)(u >> 16);
}
__device__ __forceinline__ float2 bf2x(unsigned int u) {   // [lo,hi] bf16 pair
    return make_float2(__uint_as_float(u << 16), __uint_as_float(u & 0xffff0000u));
}
__device__ __forceinline__ float sel4(float4 v, int h) {
    float r = v.x;
    r = (h == 1) ? v.y : r;
    r = (h == 2) ? v.z : r;
    r = (h == 3) ? v.w : r;
    return r;
}

// ---------------- CSR build ----------------
__global__ __launch_bounds__(TPB) void k_hist(const int* __restrict__ dst,
                                              int* __restrict__ deg, int e) {
    int i = blockIdx.x * TPB + threadIdx.x;
    if (i < e) atomicAdd(&deg[dst[i]], 1);
}

// pass 1: per-block (256-elem) sums
__global__ __launch_bounds__(TPB) void k_scan_part(const int* __restrict__ deg,
                                                   int* __restrict__ part, int n) {
    int i = blockIdx.x * TPB + threadIdx.x;
    int v = (i < n) ? deg[i] : 0;
#pragma unroll
    for (int o = 32; o > 0; o >>= 1) v += __shfl_xor(v, o);
    __shared__ int sw[4];
    if ((threadIdx.x & 63) == 0) sw[threadIdx.x >> 6] = v;
    __syncthreads();
    if (threadIdx.x == 0) part[blockIdx.x] = sw[0] + sw[1] + sw[2] + sw[3];
}

// pass 2: single block scans the (<=256) block partials -> exclusive
__global__ __launch_bounds__(TPB) void k_scan_top(int* __restrict__ part, int nb) {
    __shared__ int sm[TPB];
    int t = threadIdx.x;
    int v = (t < nb) ? part[t] : 0;
    sm[t] = v;
    __syncthreads();
    for (int off = 1; off < TPB; off <<= 1) {
        int u = (t >= off) ? sm[t - off] : 0;
        __syncthreads();
        sm[t] += u;
        __syncthreads();
    }
    if (t < nb) part[t] = sm[t] - v;  // exclusive
}

// pass 3: in-block exclusive scan + base; write row_start/cursor/dis
__global__ __launch_bounds__(TPB) void k_scan_apply(const int* __restrict__ deg,
                                                    const int* __restrict__ part,
                                                    int* __restrict__ row_start,
                                                    int* __restrict__ cursor,
                                                    float* __restrict__ dis,
                                                    int n, int e_total) {
    __shared__ int sm[TPB];
    int i = blockIdx.x * TPB + threadIdx.x;
    int t = threadIdx.x;
    int d = (i < n) ? deg[i] : 0;
    sm[t] = d;
    __syncthreads();
    for (int off = 1; off < TPB; off <<= 1) {
        int u = (t >= off) ? sm[t - off] : 0;
        __syncthreads();
        sm[t] += u;
        __syncthreads();
    }
    if (i < n) {
        int rs = part[blockIdx.x] + sm[t] - d;  // exclusive prefix
        row_start[i] = rs;
        cursor[i] = rs;
        dis[i] = rsqrtf((float)(d + 1));        // +1 self loop
    }
    if (blockIdx.x == 0 && t == 0) row_start[n] = e_total;
}

__global__ __launch_bounds__(TPB) void k_scatter(const int* __restrict__ src,
                                                 const int* __restrict__ dst,
                                                 int* __restrict__ cursor,
                                                 int* __restrict__ csr_src, int e) {
    int i = blockIdx.x * TPB + threadIdx.x;
    if (i < e) {
        int p = atomicAdd(&cursor[dst[i]], 1);
        csr_src[p] = src[i];
    }
}

// ---------------- conversions ----------------
__global__ __launch_bounds__(TPB) void k_f2bf(const float* __restrict__ in,
                                              unsigned short* __restrict__ out, int n4) {
    int i = blockIdx.x * TPB + threadIdx.x;
    if (i >= n4) return;
    float4 v = ((const float4*)in)[i];
    unsigned int p0 = (unsigned int)f2bf(v.x) | ((unsigned int)f2bf(v.y) << 16);
    unsigned int p1 = (unsigned int)f2bf(v.z) | ((unsigned int)f2bf(v.w) << 16);
    ((uint2*)out)[i] = make_uint2(p0, p1);
}

// W[k][n] fp32 -> Wt[n][k] bf16  (K=128)
__global__ __launch_bounds__(TPB) void k_wt(const float* __restrict__ W,
                                            unsigned short* __restrict__ Wt, int ocols) {
    int i = blockIdx.x * TPB + threadIdx.x;
    if (i >= 128 * ocols) return;
    int k = i / ocols, n = i - k * ocols;
    Wt[n * 128 + k] = f2bf(W[i]);
}

// ---------------- MFMA GEMM: C[node][chan] = feat[node][:] . Wt[chan][:] ----
__global__ __launch_bounds__(TPB, 2) void k_gemm_mfma(const unsigned short* __restrict__ feat,
                                                      const unsigned short* __restrict__ Wt,
                                                      unsigned short* __restrict__ C,
                                                      int nrows, int ocols) {
    __shared__ uint4 wl[2048];  // 32KB: [ks][ct][lane] fragment-linear
    int t = threadIdx.x;
    int cb = blockIdx.y << 7;
#pragma unroll
    for (int i = 0; i < 8; ++i) {
        int fi = i * 256 + t;
        int l = fi & 63, ct = (fi >> 6) & 7, ks = fi >> 9;
        int chan = cb + ct * 16 + (l & 15);
        wl[fi] = ((const uint4*)(Wt + (size_t)chan * 128))[ks * 4 + (l >> 4)];
    }
    __syncthreads();

    int wave = t >> 6, lane = t & 63;
    int wr = wave >> 1, wc = wave & 1;
    int nbase = (blockIdx.x << 7) + (wc << 6);
    const uint4* brow[4];
#pragma unroll
    for (int nt = 0; nt < 4; ++nt) {
        int node = nbase + nt * 16 + (lane & 15);
        node = node < nrows ? node : (nrows - 1);
        brow[nt] = (const uint4*)(feat + (size_t)node * 128);
    }
    f32x4 acc[4][4];
#pragma unroll
    for (int mt = 0; mt < 4; ++mt)
#pragma unroll
        for (int nt = 0; nt < 4; ++nt) acc[mt][nt] = (f32x4)0.f;

    int kq = lane >> 4;
#pragma unroll
    for (int ks = 0; ks < 4; ++ks) {
        U4S8 a[4], b[4];
#pragma unroll
        for (int mt = 0; mt < 4; ++mt)
            a[mt].u = wl[(ks * 8 + wr * 4 + mt) * 64 + lane];
#pragma unroll
        for (int nt = 0; nt < 4; ++nt)
            b[nt].u = brow[nt][ks * 4 + kq];
#pragma unroll
        for (int mt = 0; mt < 4; ++mt)
#pragma unroll
            for (int nt = 0; nt < 4; ++nt)
                acc[mt][nt] = __builtin_amdgcn_mfma_f32_16x16x32_bf16(
                    a[mt].s, b[nt].s, acc[mt][nt], 0, 0, 0);
    }
#pragma unroll
    for (int nt = 0; nt < 4; ++nt) {
        int node = nbase + nt * 16 + (lane & 15);
        if (node >= nrows) continue;
#pragma unroll
        for (int mt = 0; mt < 4; ++mt) {
            int chan = cb + (wr << 6) + mt * 16 + (lane >> 4) * 4;
            f32x4 v = acc[mt][nt];
            unsigned int p0 = (unsigned int)f2bf(v.x) | ((unsigned int)f2bf(v.y) << 16);
            unsigned int p1 = (unsigned int)f2bf(v.z) | ((unsigned int)f2bf(v.w) << 16);
            *(uint2*)(C + (size_t)node * ocols + chan) = make_uint2(p0, p1);
        }
    }
}

// ---------------- fused GCN: bf16 gather + self + bias + LN + ReLU -> bf16 --
__global__ __launch_bounds__(TPB) void k_gcn_fused(const unsigned short* __restrict__ hb,
                                                   const int* __restrict__ csr_src,
                                                   const int* __restrict__ row_start,
                                                   const float* __restrict__ dis,
                                                   const float* __restrict__ b,
                                                   const float* __restrict__ g,
                                                   const float* __restrict__ beta,
                                                   unsigned short* __restrict__ out, int n) {
    __shared__ int   ssrc[4][64];
    __shared__ float swt[4][64];
    int node = (blockIdx.x * TPB + threadIdx.x) >> 6;
    int lane = threadIdx.x & 63;
    int wid = threadIdx.x >> 6;
    if (node >= n) return;
    int s0 = row_start[node], s1 = row_start[node + 1];
    float dn = dis[node];
    const unsigned int* hu = (const unsigned int*)hb;
    float2 acc = make_float2(0.f, 0.f);
    for (int base = s0; base < s1; base += 64) {
        int cnt = min(64, s1 - base);
        int sidx = 0; float w = 0.f;
        if (lane < cnt) { sidx = csr_src[base + lane]; w = dis[sidx]; }
        ssrc[wid][lane] = sidx;
        swt[wid][lane] = w;
        for (int j = 0; j < cnt; ++j) {
            int s = ssrc[wid][j];
            float wj = swt[wid][j];
            float2 v = bf2x(hu[(size_t)s * 64 + lane]);
            acc.x += wj * v.x;
            acc.y += wj * v.y;
        }
    }
    float sl = dn * dn;
    float2 hv = bf2x(hu[(size_t)node * 64 + lane]);
    float2 bv = ((const float2*)b)[lane];
    float vx = dn * acc.x + sl * hv.x + bv.x;
    float vy = dn * acc.y + sl * hv.y + bv.y;
    float s = vx + vy, sq = vx * vx + vy * vy;
#pragma unroll
    for (int o = 32; o > 0; o >>= 1) {
        s  += __shfl_xor(s, o);
        sq += __shfl_xor(sq, o);
    }
    float mu = s * (1.f / 128.f);
    float var = sq * (1.f / 128.f) - mu * mu;
    float rstd = rsqrtf(var + 1e-5f);
    float2 gv  = ((const float2*)g)[lane];
    float2 btv = ((const float2*)beta)[lane];
    float ox = fmaxf((vx - mu) * rstd * gv.x + btv.x, 0.f);
    float oy = fmaxf((vy - mu) * rstd * gv.y + btv.y, 0.f);
    ((unsigned int*)out)[(size_t)node * 64 + lane] =
        (unsigned int)f2bf(ox) | ((unsigned int)f2bf(oy) << 16);
}

// ---------------- GAT attention dots (bf16 hg) ------------------------------
__global__ __launch_bounds__(TPB) void k_att_dots(const unsigned short* __restrict__ hgb,
                                                  const float* __restrict__ att_s,
                                                  const float* __restrict__ att_d,
                                                  float* __restrict__ a_s,
                                                  float* __restrict__ a_d, int n) {
    int wave = (blockIdx.x * TPB + threadIdx.x) >> 6;
    int lane = threadIdx.x & 63;
    if (wave >= n) return;
    int h = lane >> 4, j = lane & 15;
    const uint4* hq = (const uint4*)hgb;
    uint4 u = hq[(size_t)wave * 64 + lane];
    float2 p0 = bf2x(u.x), p1 = bf2x(u.y), p2 = bf2x(u.z), p3 = bf2x(u.w);
    const float4* s4 = (const float4*)(att_s + h * 128 + j * 8);
    const float4* d4 = (const float4*)(att_d + h * 128 + j * 8);
    float4 s0 = s4[0], s1 = s4[1];
    float4 d0 = d4[0], d1 = d4[1];
    float ps = p0.x * s0.x + p0.y * s0.y + p1.x * s0.z + p1.y * s0.w
             + p2.x * s1.x + p2.y * s1.y + p3.x * s1.z + p3.y * s1.w;
    float pd = p0.x * d0.x + p0.y * d0.y + p1.x * d0.z + p1.y * d0.w
             + p2.x * d1.x + p2.y * d1.y + p3.x * d1.z + p3.y * d1.w;
#pragma unroll
    for (int o = 8; o > 0; o >>= 1) {
        ps += __shfl_xor(ps, o);
        pd += __shfl_xor(pd, o);
    }
    if (j == 0) {
        a_s[wave * 4 + h] = ps;
        a_d[wave * 4 + h] = pd;
    }
}

// ---------------- fused GAT: single-pass softmax + bf16 gather + head mean --
__global__ __launch_bounds__(TPB) void k_gat_fused(const unsigned short* __restrict__ hgb,
                                                   const float* __restrict__ a_s,
                                                   const float* __restrict__ a_d,
                                                   const int* __restrict__ csr_src,
                                                   const int* __restrict__ row_start,
                                                   float* __restrict__ out, int n) {
    __shared__ int   ssrc[4][64];
    __shared__ float swt[4][4][65];
    int node = (blockIdx.x * TPB + threadIdx.x) >> 6;
    int lane = threadIdx.x & 63;
    int wid = threadIdx.x >> 6;
    if (node >= n) return;
    int s0 = row_start[node], s1 = row_start[node + 1];
    int h = lane >> 4;
    const float4* as4 = (const float4*)a_s;
    float4 ad = ((const float4*)a_d)[node];
    float4 asn = as4[node];
    float4 wself;
    wself.x = __expf(lrelu(asn.x + ad.x));
    wself.y = __expf(lrelu(asn.y + ad.y));
    wself.z = __expf(lrelu(asn.z + ad.z));
    wself.w = __expf(lrelu(asn.w + ad.w));
    const uint4* hq = (const uint4*)hgb;
    float acc[8];
    {
        float wsh = sel4(wself, h);
        uint4 u = hq[(size_t)node * 64 + lane];
        float2 p0 = bf2x(u.x), p1 = bf2x(u.y), p2 = bf2x(u.z), p3 = bf2x(u.w);
        acc[0] = wsh * p0.x; acc[1] = wsh * p0.y;
        acc[2] = wsh * p1.x; acc[3] = wsh * p1.y;
        acc[4] = wsh * p2.x; acc[5] = wsh * p2.y;
        acc[6] = wsh * p3.x; acc[7] = wsh * p3.y;
    }
    float4 den = make_float4(0.f, 0.f, 0.f, 0.f);
    for (int base = s0; base < s1; base += 64) {
        int cnt = min(64, s1 - base);
        int sidx = 0;
        float4 w4 = make_float4(0.f, 0.f, 0.f, 0.f);
        if (lane < cnt) {
            sidx = csr_src[base + lane];
            float4 a = as4[sidx];
            w4.x = __expf(lrelu(a.x + ad.x));
            w4.y = __expf(lrelu(a.y + ad.y));
            w4.z = __expf(lrelu(a.z + ad.z));
            w4.w = __expf(lrelu(a.w + ad.w));
            den.x += w4.x; den.y += w4.y; den.z += w4.z; den.w += w4.w;
        }
        ssrc[wid][lane] = sidx;
        swt[wid][0][lane] = w4.x;
        swt[wid][1][lane] = w4.y;
        swt[wid][2][lane] = w4.z;
        swt[wid][3][lane] = w4.w;
        for (int j = 0; j < cnt; ++j) {
            int s = ssrc[wid][j];
            float wj = swt[wid][h][j];
            uint4 u = hq[(size_t)s * 64 + lane];
            float2 p0 = bf2x(u.x), p1 = bf2x(u.y), p2 = bf2x(u.z), p3 = bf2x(u.w);
            acc[0] += wj * p0.x; acc[1] += wj * p0.y;
            acc[2] += wj * p1.x; acc[3] += wj * p1.y;
            acc[4] += wj * p2.x; acc[5] += wj * p2.y;
            acc[6] += wj * p3.x; acc[7] += wj * p3.y;
        }
    }
#pragma unroll
    for (int o = 32; o > 0; o >>= 1) {
        den.x += __shfl_xor(den.x, o);
        den.y += __shfl_xor(den.y, o);
        den.z += __shfl_xor(den.z, o);
        den.w += __shfl_xor(den.w, o);
    }
    den.x += wself.x; den.y += wself.y; den.z += wself.z; den.w += wself.w;
    float winv = 0.25f / sel4(den, h);
#pragma unroll
    for (int j = 0; j < 8; ++j) acc[j] *= winv;
#pragma unroll
    for (int j = 0; j < 8; ++j) acc[j] += __shfl_xor(acc[j], 16);
#pragma unroll
    for (int j = 0; j < 8; ++j) acc[j] += __shfl_xor(acc[j], 32);
    if (lane < 16) {
        float4* o4 = (float4*)(out + (size_t)node * 128 + lane * 8);
        o4[0] = make_float4(acc[0], acc[1], acc[2], acc[3]);
        o4[1] = make_float4(acc[4], acc[5], acc[6], acc[7]);
    }
}

// ---------------- final bias+relu, node embeddings, pooled run-atomics ------
__global__ __launch_bounds__(TPB) void k_final_pool(const float* __restrict__ acc,
                                                    const float* __restrict__ gat_b,
                                                    const int* __restrict__ batch,
                                                    float* __restrict__ node_out,
                                                    float* __restrict__ mean_acc,
                                                    float* __restrict__ max_acc,
                                                    float* __restrict__ cnt, int n) {
    int wave = (blockIdx.x * TPB + threadIdx.x) >> 6;
    int lane = threadIdx.x & 63;
    int n0 = wave * 16;
    if (n0 >= n) return;
    int n1 = min(n0 + 16, n);
    float2 bv = ((const float2*)gat_b)[lane];
    float2 bsum = make_float2(0.f, 0.f), bmax = make_float2(0.f, 0.f);
    int cur_g = batch[n0];
    int cntloc = 0;
    for (int nn = n0; nn < n1; ++nn) {
        int g = batch[nn];
        if (g != cur_g) {
            float* ma = mean_acc + cur_g * 128 + lane * 2;
            atomicAdd(ma + 0, bsum.x);
            atomicAdd(ma + 1, bsum.y);
            int* mxp = (int*)(max_acc + cur_g * 128 + lane * 2);
            atomicMax(mxp + 0, __float_as_int(bmax.x));
            atomicMax(mxp + 1, __float_as_int(bmax.y));
            if (lane == 0) atomicAdd(&cnt[cur_g], (float)cntloc);
            bsum = make_float2(0.f, 0.f);
            bmax = make_float2(0.f, 0.f);
            cntloc = 0;
            cur_g = g;
        }
        float2 a = ((const float2*)acc)[nn * 64 + lane];
        float2 o = make_float2(fmaxf(a.x + bv.x, 0.f), fmaxf(a.y + bv.y, 0.f));
        ((float2*)node_out)[nn * 64 + lane] = o;
        bsum.x += o.x; bsum.y += o.y;
        bmax.x = fmaxf(bmax.x, o.x); bmax.y = fmaxf(bmax.y, o.y);
        ++cntloc;
    }
    float* ma = mean_acc + cur_g * 128 + lane * 2;
    atomicAdd(ma + 0, bsum.x);
    atomicAdd(ma + 1, bsum.y);
    int* mxp = (int*)(max_acc + cur_g * 128 + lane * 2);
    atomicMax(mxp + 0, __float_as_int(bmax.x));
    atomicMax(mxp + 1, __float_as_int(bmax.y));
    if (lane == 0) atomicAdd(&cnt[cur_g], (float)cntloc);
}

__global__ __launch_bounds__(TPB) void k_pool_final(const float* __restrict__ mean_acc,
                                                    const float* __restrict__ max_acc,
                                                    const float* __restrict__ cnt,
                                                    float* __restrict__ gout, int g128) {
    int i = blockIdx.x * TPB + threadIdx.x;
    if (i >= g128) return;
    int g = i >> 7, d = i & 127;
    float c = fmaxf(cnt[g], 1.f);
    gout[g * 256 + d] = mean_acc[i] / c;
    gout[g * 256 + 128 + d] = max_acc[i];
}

// ---------------------------------------------------------------------------
extern "C" void kernel_launch(void* const* d_in, const int* in_sizes, int n_in,
                              void* d_out, int out_size, void* d_ws, size_t ws_size,
                              hipStream_t stream) {
    const float* x       = (const float*)d_in[0];
    const int*   ei      = (const int*)d_in[1];
    const int*   batch   = (const int*)d_in[2];
    const float* W1      = (const float*)d_in[3];
    const float* b1      = (const float*)d_in[4];
    const float* g1      = (const float*)d_in[5];
    const float* beta1   = (const float*)d_in[6];
    const float* W2      = (const float*)d_in[7];
    const float* b2      = (const float*)d_in[8];
    const float* g2      = (const float*)d_in[9];
    const float* beta2   = (const float*)d_in[10];
    const float* gat_W   = (const float*)d_in[11];
    const float* att_src = (const float*)d_in[12];
    const float* att_dst = (const float*)d_in[13];
    const float* gat_b   = (const float*)d_in[14];

    const int N = in_sizes[0] / 128;
    const int E = in_sizes[1] / 2;
    const int G = (out_size - N * 128) / 256;
    const int* src = ei;
    const int* dst = ei + E;

    float* ws = (float*)d_ws;
    float* dis      = ws; ws += N;
    float* Bf       = ws; ws += (size_t)N * 128;   // GAT out (fp32)
    float* a_s      = ws; ws += N * 4;
    float* a_d      = ws; ws += N * 4;
    float* mean_acc = ws; ws += G * 128;
    float* max_acc  = ws; ws += G * 128;
    float* cnt      = ws; ws += G;
    unsigned short* xb  = (unsigned short*)ws; ws += (size_t)N * 64;
    unsigned short* Hbf = (unsigned short*)ws; ws += (size_t)N * 64;
    unsigned short* Bbf = (unsigned short*)ws; ws += (size_t)N * 64;
    unsigned short* Cbf = (unsigned short*)ws; ws += (size_t)N * 64;
    unsigned short* hgb = (unsigned short*)ws; ws += (size_t)N * 256;
    unsigned short* Wt1 = (unsigned short*)ws; ws += 128 * 64;
    unsigned short* Wt2 = (unsigned short*)ws; ws += 128 * 64;
    unsigned short* Wtg = (unsigned short*)ws; ws += 512 * 64;
    int* deg       = (int*)ws; ws += N;
    int* part      = (int*)ws; ws += 256;
    int* row_start = (int*)ws; ws += N + 1;
    int* cursor    = (int*)ws; ws += N + 1;
    int* csr_src   = (int*)ws; ws += E;

    float* gout = (float*)d_out;        // [G, 256]
    float* node_out = gout + G * 256;   // [N, 128]

    auto cdiv = [](long a, long b) { return (int)((a + b - 1) / b); };
    const int nb = cdiv(N, TPB);

    // CSR build (by dst) + degrees; parallel 3-pass scan
    hipMemsetAsync(deg, 0, (size_t)N * 4, stream);
    k_hist<<<cdiv(E, TPB), TPB, 0, stream>>>(dst, deg, E);
    k_scan_part<<<nb, TPB, 0, stream>>>(deg, part, N);
    k_scan_top<<<1, TPB, 0, stream>>>(part, nb);
    k_scan_apply<<<nb, TPB, 0, stream>>>(deg, part, row_start, cursor, dis, N, E);
    k_scatter<<<cdiv(E, TPB), TPB, 0, stream>>>(src, dst, cursor, csr_src, E);

    // conversions
    k_f2bf<<<cdiv((long)N * 32, TPB), TPB, 0, stream>>>(x, xb, N * 32);
    k_wt<<<cdiv(128 * 128, TPB), TPB, 0, stream>>>(W1, Wt1, 128);
    k_wt<<<cdiv(128 * 128, TPB), TPB, 0, stream>>>(W2, Wt2, 128);
    k_wt<<<cdiv(128 * 512, TPB), TPB, 0, stream>>>(gat_W, Wtg, 512);

    // GCN layer 1
    k_gemm_mfma<<<dim3(cdiv(N, 128), 1), TPB, 0, stream>>>(xb, Wt1, Hbf, N, 128);
    k_gcn_fused<<<cdiv((long)N * 64, TPB), TPB, 0, stream>>>(Hbf, csr_src, row_start, dis,
                                                             b1, g1, beta1, Bbf, N);
    // GCN layer 2
    k_gemm_mfma<<<dim3(cdiv(N, 128), 1), TPB, 0, stream>>>(Bbf, Wt2, Hbf, N, 128);
    k_gcn_fused<<<cdiv((long)N * 64, TPB), TPB, 0, stream>>>(Hbf, csr_src, row_start, dis,
                                                             b2, g2, beta2, Cbf, N);
    // GAT
    k_gemm_mfma<<<dim3(cdiv(N, 128), 4), TPB, 0, stream>>>(Cbf, Wtg, hgb, N, 512);
    k_att_dots<<<cdiv((long)N * 64, TPB), TPB, 0, stream>>>(hgb, att_src, att_dst, a_s, a_d, N);
    k_gat_fused<<<cdiv((long)N * 64, TPB), TPB, 0, stream>>>(hgb, a_s, a_d, csr_src, row_start, Bf, N);

    // final + pooling
    hipMemsetAsync(mean_acc, 0, (size_t)(G * 256 + G) * 4, stream);
    k_final_pool<<<cdiv((long)cdiv(N, 16) * 64, TPB), TPB, 0, stream>>>(Bf, gat_b, batch, node_out,
                                                                        mean_acc, max_acc, cnt, N);
    k_pool_final<<<cdiv((long)G * 128, TPB), TPB, 0, stream>>>(mean_acc, max_acc, cnt, gout, G * 128);
}